// Round 1
// baseline (1242.864 us; speedup 1.0000x reference)
//
#include <hip/hip_runtime.h>
#include <stdint.h>

typedef unsigned short u16;
typedef unsigned int u32;
typedef __attribute__((ext_vector_type(4))) float f32x4;
typedef __attribute__((ext_vector_type(4))) float float4v;
typedef __attribute__((ext_vector_type(8))) short short8;
typedef __attribute__((ext_vector_type(4))) u32 u32x4;
typedef __attribute__((ext_vector_type(4))) u16 u16x4;
typedef __attribute__((ext_vector_type(8))) u16 u16x8;

#define DEV static __device__ __forceinline__

#define NTOK 3137
#define MROWS 12548
#define NHEAD 16
#define DH 64

DEV float bf2f(u16 h){ u32 u = ((u32)h)<<16; float f; __builtin_memcpy(&f,&u,4); return f; }
DEV u16 f2bf(float f){ u32 u; __builtin_memcpy(&u,&f,4); u32 r = u + 0x7FFFu + ((u>>16)&1u); return (u16)(r>>16); }

DEV void gl_lds16(const u16* g, u16* l){
  __builtin_amdgcn_global_load_lds((const __attribute__((address_space(1))) void*)g,
                                   (__attribute__((address_space(3))) void*)l, 16, 0, 0);
}

// ---------------- cast fp32 -> bf16 (vectorized) ----------------
__global__ __launch_bounds__(256) void cast_bf16_kernel(const float* __restrict__ in,
                                                        u16* __restrict__ out, int n4){
  int i = blockIdx.x*256 + threadIdx.x;
  int stride = gridDim.x*256;
  for(; i < n4; i += stride){
    float4v v = *(const float4v*)(in + (size_t)i*4);
    u16x4 o;
    for(int e=0;e<4;++e) o[e] = f2bf(v[e]);
    *(u16x4*)(out + (size_t)i*4) = o;
  }
}

// ---------------- transpose + cast: out[c][r] = bf16(in[r][c]) ----------------
__global__ void transpose_cast_kernel(const float* __restrict__ in, u16* __restrict__ out,
                                      int R, int C){
  __shared__ float tile[32][33];
  int c0 = blockIdx.x<<5, r0 = blockIdx.y<<5;
  int tx = threadIdx.x, ty = threadIdx.y;
  for(int k=0;k<32;k+=8) tile[ty+k][tx] = in[(size_t)(r0+ty+k)*C + c0+tx];
  __syncthreads();
  for(int k=0;k<32;k+=8) out[(size_t)(c0+ty+k)*R + r0+tx] = f2bf(tile[tx][ty+k]);
}

// ---------------- GEMM: C[M][N] = A[M][1024] * Bt[N][1024]^T, bf16 MFMA ----------------
// EPI==0: scatter into Q(*0.125)/K/V [b*16+h][tok][64] bf16.  EPI==1: fp32 store to Out.
template<int EPI>
__global__ __launch_bounds__(256) void gemm_kernel(
    const u16* __restrict__ A, const u16* __restrict__ Bt,
    u16* __restrict__ Qb, u16* __restrict__ Kb, u16* __restrict__ Vb,
    float* __restrict__ Out, int Mtot)
{
  __shared__ u16 lA[128*32];
  __shared__ u16 lB[128*32];
  const int tid = threadIdx.x, lane = tid & 63, wv = tid >> 6;
  const int m0 = blockIdx.y<<7, n0 = blockIdx.x<<7;
  const int wm = (wv>>1)<<6, wn = (wv&1)<<6;
  f32x4 acc[4][4];
  for(int i=0;i<4;++i) for(int j=0;j<4;++j) acc[i][j] = (f32x4){0.f,0.f,0.f,0.f};

  for(int kt=0; kt<32; ++kt){
    const int k0 = kt<<5;
    __syncthreads();
    // stage 16 x 1KB chunks: A tile [128][32], B tile [128][32] (Bt rows). wave-uniform LDS base.
    for(int cc=0; cc<4; ++cc){
      int c = (wv<<2) + cc;                 // 0..15
      int row = ((c&7)<<4) + (lane>>2);
      int slot = lane & 3;
      if(c < 8){
        int gr = m0 + row; if(gr >= Mtot) gr = Mtot-1;
        gl_lds16(A + (size_t)gr*1024 + k0 + (slot<<3), lA + (c<<9));
      } else {
        int gr = n0 + row;
        gl_lds16(Bt + (size_t)gr*1024 + k0 + (slot<<3), lB + ((c-8)<<9));
      }
    }
    __syncthreads();
    short8 af[4], bfr[4];
    for(int i=0;i<4;++i){
      int r  = wm + (i<<4) + (lane&15);
      af[i]  = *(const short8*)&lA[(r<<5) + ((lane>>4)<<3)];
      int cn = wn + (i<<4) + (lane&15);
      bfr[i] = *(const short8*)&lB[(cn<<5) + ((lane>>4)<<3)];
    }
    for(int i=0;i<4;++i)
      for(int j=0;j<4;++j)
        acc[i][j] = __builtin_amdgcn_mfma_f32_16x16x32_bf16(af[i], bfr[j], acc[i][j], 0,0,0);
  }

  if constexpr(EPI==0){
    for(int i=0;i<4;++i){
      int mb = m0 + wm + (i<<4) + ((lane>>4)<<2);
      for(int j=0;j<4;++j){
        int col = n0 + wn + (j<<4) + (lane&15);
        int which = col>>10, rem = col&1023;
        int h = rem>>6, d = rem&63;
        float sc = (which==0) ? 0.125f : 1.0f;
        u16* dst = (which==0)?Qb:((which==1)?Kb:Vb);
        for(int r=0;r<4;++r){
          int mm = mb + r;
          if(mm < Mtot){
            int b = mm/NTOK, tok = mm - b*NTOK;
            dst[((size_t)(b*NHEAD+h)*NTOK + tok)*DH + d] = f2bf(acc[i][j][r]*sc);
          }
        }
      }
    }
  } else {
    for(int i=0;i<4;++i){
      int mb = m0 + wm + (i<<4) + ((lane>>4)<<2);
      for(int j=0;j<4;++j){
        int col = n0 + wn + (j<<4) + (lane&15);
        for(int r=0;r<4;++r){
          int mm = mb + r;
          if(mm < Mtot) Out[(size_t)mm*1024 + col] = acc[i][j][r];
        }
      }
    }
  }
}

// ---------------- cls-token attention: 64 blocks (one per b*16+h) ----------------
__global__ __launch_bounds__(256) void cls_attn_kernel(
    const u16* __restrict__ Qb, const u16* __restrict__ Kb, const u16* __restrict__ Vb,
    u16* __restrict__ Abuf)
{
  __shared__ float qs[64];
  __shared__ float rm[4], rl[4];
  __shared__ float racc[4][64];
  const int tid = threadIdx.x, lane = tid & 63, wv = tid >> 6;
  const int bh = blockIdx.x;
  const u16* Kh = Kb + (size_t)bh*NTOK*DH;
  const u16* Vh = Vb + (size_t)bh*NTOK*DH;
  if(tid < 64) qs[tid] = bf2f(Qb[(size_t)bh*NTOK*DH + tid]);   // q already *0.125
  __syncthreads();
  float m = -1e30f, lsum = 0.f, accd = 0.f;
  for(int c=0;c<13;++c){
    int j = c*256 + wv*64 + lane;
    float s = -1e30f;
    if(j < NTOK){
      const u16* kr = Kh + (size_t)j*DH;
      float dot = 0.f;
      for(int t=0;t<8;++t){
        u32x4 kv = *(const u32x4*)(kr + t*8);
        for(int w=0;w<4;++w){
          u32 word = kv[w];
          u32 ulo = word<<16, uhi = word & 0xFFFF0000u;
          float lo, hi; __builtin_memcpy(&lo,&ulo,4); __builtin_memcpy(&hi,&uhi,4);
          dot += lo*qs[t*8 + 2*w] + hi*qs[t*8 + 2*w + 1];
        }
      }
      s = dot;
    }
    float cmax = s;
    for(int off=1; off<64; off<<=1) cmax = fmaxf(cmax, __shfl_xor(cmax, off));
    float mnew = fmaxf(m, cmax);
    float p = (j < NTOK) ? __expf(s - mnew) : 0.f;
    float psum = p;
    for(int off=1; off<64; off<<=1) psum += __shfl_xor(psum, off);
    float sc = __expf(m - mnew);
    lsum = lsum*sc + psum;
    accd *= sc;
    int jb = c*256 + wv*64;
    for(int jj=0;jj<64;++jj){
      int j2 = jb + jj;
      if(j2 >= NTOK) break;
      float pj = __shfl(p, jj);
      accd += pj * bf2f(Vh[(size_t)j2*DH + lane]);
    }
    m = mnew;
  }
  if(lane==0){ rm[wv]=m; rl[wv]=lsum; }
  racc[wv][lane] = accd;
  __syncthreads();
  if(wv==0){
    float M = fmaxf(fmaxf(rm[0],rm[1]), fmaxf(rm[2],rm[3]));
    float L=0.f, Av=0.f;
    for(int wi=0; wi<4; ++wi){
      float e = __expf(rm[wi]-M);
      L += rl[wi]*e; Av += racc[wi][lane]*e;
    }
    int b = bh>>4, h = bh&15;
    Abuf[(size_t)b*NTOK*1024 + h*DH + lane] = f2bf(Av/L);   // token 0
  }
}

// ---------------- axial attention: 1024 blocks (one per (b*16+h, frame)) ----------------
// keys = [cls] + 196 frame tokens (197, padded to 208/224); queries = 196 frame tokens.
__global__ __launch_bounds__(256) void axial_attn_kernel(
    const u16* __restrict__ Qb, const u16* __restrict__ Kb, const u16* __restrict__ Vb,
    u16* __restrict__ Abuf)
{
  __shared__ u16 lV[64*232];      // V^T: lV[d][ktok], ktok 0..223 (>=197 zero). 232-pad: uniform-8 bank slots
  __shared__ u16 lP[4*16*232];    // per-wave P tile [16 q rows][224 ktok], bf16
  const int tid = threadIdx.x, lane = tid & 63, wv = tid >> 6;
  const int bf = blockIdx.x, bh = bf >> 4, fi = bf & 15;
  const u16* Kh = Kb + (size_t)bh*NTOK*DH;
  const u16* Vh = Vb + (size_t)bh*NTOK*DH;
  const u16* Qh = Qb + (size_t)bh*NTOK*DH;

  // stage V^T (scalar transpose writes; once per block)
  for(int c = tid; c < 224*8; c += 256){
    int tok = c >> 3, slot = c & 7;
    u16 vals[8];
    if(tok <= 196){
      size_t row = (tok==0) ? 0 : (size_t)(fi*196 + tok)*DH;
      u16x8 v = *(const u16x8*)(Vh + row + slot*8);
      for(int e=0;e<8;++e) vals[e] = v[e];
    } else {
      for(int e=0;e<8;++e) vals[e] = 0;
    }
    for(int e=0;e<8;++e) lV[(slot*8+e)*232 + tok] = vals[e];
  }
  // zero P pad cols 208..223 (never rewritten)
  for(int c = tid; c < 4*16*16; c += 256){
    int w2 = c >> 8, rem = c & 255, row = rem >> 4, cc = rem & 15;
    lP[w2*(16*232) + row*232 + 208 + cc] = 0;
  }
  __syncthreads();

  u16* myP = lP + wv*(16*232);
  const int b_i = bh >> 4, h = bh & 15;

  for(int qt = wv; qt < 13; qt += 4){
    // Q A-frags (rows clamped at 195; garbage rows masked on store)
    int qr = qt*16 + (lane&15);
    int qrc = qr < 196 ? qr : 195;
    size_t qrow = (size_t)(1 + fi*196 + qrc)*DH;
    short8 qa0 = *(const short8*)(Qh + qrow + ((lane>>4)<<3));
    short8 qa1 = *(const short8*)(Qh + qrow + 32 + ((lane>>4)<<3));

    // S = Q K^T  (B-frags straight from global K rows: contiguous in d)
    f32x4 s[13];
    for(int t=0;t<13;++t){
      int tok = t*16 + (lane&15);
      int tokc = tok < 197 ? tok : 196;
      size_t krow = (tokc==0) ? 0 : (size_t)(fi*196 + tokc)*DH;
      short8 b0 = *(const short8*)(Kh + krow + ((lane>>4)<<3));
      short8 b1 = *(const short8*)(Kh + krow + 32 + ((lane>>4)<<3));
      f32x4 z = {0.f,0.f,0.f,0.f};
      z = __builtin_amdgcn_mfma_f32_16x16x32_bf16(qa0, b0, z, 0,0,0);
      z = __builtin_amdgcn_mfma_f32_16x16x32_bf16(qa1, b1, z, 0,0,0);
      s[t] = z;
    }
    int mycol = lane & 15;
    if(192 + mycol >= 197)
      for(int r=0;r<4;++r) s[12][r] = -1e30f;      // mask padded key cols

    // row softmax (rows live in 16-lane groups)
    f32x4 mx = s[0];
    for(int t=1;t<13;++t) for(int r=0;r<4;++r) mx[r] = fmaxf(mx[r], s[t][r]);
    for(int off=1; off<16; off<<=1)
      for(int r=0;r<4;++r) mx[r] = fmaxf(mx[r], __shfl_xor(mx[r], off));
    f32x4 lsum = {0.f,0.f,0.f,0.f};
    for(int t=0;t<13;++t) for(int r=0;r<4;++r){
      float p = __expf(s[t][r] - mx[r]); s[t][r] = p; lsum[r] += p;
    }
    for(int off=1; off<16; off<<=1)
      for(int r=0;r<4;++r) lsum[r] += __shfl_xor(lsum[r], off);

    // P -> LDS (bf16, C-layout scatter; same-wave ordering handled by compiler)
    for(int t=0;t<13;++t){
      int tok = t*16 + mycol;
      for(int r=0;r<4;++r) myP[(((lane>>4)<<2)+r)*232 + tok] = f2bf(s[t][r]);
    }

    // O = P V   (A-frags from myP rows, B-frags from V^T rows — both ds_read_b128)
    f32x4 o[4] = {{0.f,0.f,0.f,0.f},{0.f,0.f,0.f,0.f},{0.f,0.f,0.f,0.f},{0.f,0.f,0.f,0.f}};
    for(int t2=0;t2<7;++t2){
      short8 a = *(const short8*)&myP[(lane&15)*232 + t2*32 + ((lane>>4)<<3)];
      for(int nd=0;nd<4;++nd){
        short8 b = *(const short8*)&lV[(nd*16 + (lane&15))*232 + t2*32 + ((lane>>4)<<3)];
        o[nd] = __builtin_amdgcn_mfma_f32_16x16x32_bf16(a, b, o[nd], 0,0,0);
      }
    }

    // store (normalize by row sum)
    for(int nd=0; nd<4; ++nd){
      int d = nd*16 + (lane&15);
      for(int r=0;r<4;++r){
        int ql = qt*16 + ((lane>>4)<<2) + r;
        if(ql < 196){
          int tok = 1 + fi*196 + ql;
          Abuf[((size_t)b_i*NTOK + tok)*1024 + h*DH + d] = f2bf(o[nd][r] / lsum[r]);
        }
      }
    }
  }
}

// ---------------- launcher ----------------
extern "C" void kernel_launch(void* const* d_in, const int* in_sizes, int n_in,
                              void* d_out, int out_size, void* d_ws, size_t ws_size,
                              hipStream_t stream) {
  const float* x     = (const float*)d_in[0];
  const float* wqkv  = (const float*)d_in[1];
  const float* wout  = (const float*)d_in[2];
  float* out = (float*)d_out;
  char* ws = (char*)d_ws;

  // workspace layout (bytes); Abuf aliases xb (xb dead after gemm<0>)
  u16* xb     = (u16*)(ws);                      // 25,698,304  [M][1024] bf16
  u16* Abuf   = xb;                              // attn output [b][tok][h*64+d] bf16
  u16* wqkvT  = (u16*)(ws + 25698304);           //  6,291,456  [3072][1024] bf16
  u16* woutT  = (u16*)(ws + 31989760);           //  2,097,152  [1024][1024] bf16
  u16* Qb     = (u16*)(ws + 34086912);           // 25,698,304  [64][3137][64] bf16 (scaled)
  u16* Kb     = (u16*)(ws + 59785216);
  u16* Vb     = (u16*)(ws + 85483520);           // end 111,181,824

  cast_bf16_kernel<<<dim3(2048), dim3(256), 0, stream>>>(x, xb, (MROWS*1024)/4);
  transpose_cast_kernel<<<dim3(96,32), dim3(32,8), 0, stream>>>(wqkv, wqkvT, 1024, 3072);
  transpose_cast_kernel<<<dim3(32,32), dim3(32,8), 0, stream>>>(wout, woutT, 1024, 1024);

  gemm_kernel<0><<<dim3(24,99), dim3(256), 0, stream>>>(xb, wqkvT, Qb, Kb, Vb, nullptr, MROWS);

  cls_attn_kernel<<<dim3(64), dim3(256), 0, stream>>>(Qb, Kb, Vb, Abuf);
  axial_attn_kernel<<<dim3(1024), dim3(256), 0, stream>>>(Qb, Kb, Vb, Abuf);

  gemm_kernel<1><<<dim3(8,99), dim3(256), 0, stream>>>(Abuf, woutT, nullptr, nullptr, nullptr, out, MROWS);
}

// Round 2
// 518.395 us; speedup vs baseline: 2.3975x; 2.3975x over previous
//
#include <hip/hip_runtime.h>
#include <stdint.h>

typedef unsigned short u16;
typedef unsigned int u32;
typedef __attribute__((ext_vector_type(4))) float f32x4;
typedef __attribute__((ext_vector_type(4))) float float4v;
typedef __attribute__((ext_vector_type(8))) short short8;
typedef __attribute__((ext_vector_type(4))) u32 u32x4;
typedef __attribute__((ext_vector_type(4))) u16 u16x4;
typedef __attribute__((ext_vector_type(8))) u16 u16x8;

#define DEV static __device__ __forceinline__

#define NTOK 3137
#define MROWS 12548
#define NHEAD 16
#define DH 64

DEV float bf2f(u16 h){ u32 u = ((u32)h)<<16; float f; __builtin_memcpy(&f,&u,4); return f; }
DEV u16 f2bf(float f){ u32 u; __builtin_memcpy(&u,&f,4); u32 r = u + 0x7FFFu + ((u>>16)&1u); return (u16)(r>>16); }

DEV void gl_lds16(const u16* g, u16* l){
  __builtin_amdgcn_global_load_lds((const __attribute__((address_space(1))) void*)g,
                                   (__attribute__((address_space(3))) void*)l, 16, 0, 0);
}

// ---------------- cast fp32 -> bf16 (vectorized) ----------------
__global__ __launch_bounds__(256) void cast_bf16_kernel(const float* __restrict__ in,
                                                        u16* __restrict__ out, int n4){
  int i = blockIdx.x*256 + threadIdx.x;
  int stride = gridDim.x*256;
  for(; i < n4; i += stride){
    float4v v = *(const float4v*)(in + (size_t)i*4);
    u16x4 o;
    for(int e=0;e<4;++e) o[e] = f2bf(v[e]);
    *(u16x4*)(out + (size_t)i*4) = o;
  }
}

// ---------------- transpose + cast: out[c][r] = bf16(in[r][c]) ----------------
__global__ void transpose_cast_kernel(const float* __restrict__ in, u16* __restrict__ out,
                                      int R, int C){
  __shared__ float tile[32][33];
  int c0 = blockIdx.x<<5, r0 = blockIdx.y<<5;
  int tx = threadIdx.x, ty = threadIdx.y;
  for(int k=0;k<32;k+=8) tile[ty+k][tx] = in[(size_t)(r0+ty+k)*C + c0+tx];
  __syncthreads();
  for(int k=0;k<32;k+=8) out[(size_t)(c0+ty+k)*R + r0+tx] = f2bf(tile[tx][ty+k]);
}

// ---------------- GEMM: C[M][N] = A[M][1024] * Bt[N][1024]^T, bf16 MFMA ----------------
// EPI==0: Q(*0.125)/K/V [b*16+h][tok][64] bf16, LDS-staged coalesced stores.
// EPI==1: fp32 Out, LDS-staged coalesced stores.
template<int EPI>
__global__ __launch_bounds__(256) void gemm_kernel(
    const u16* __restrict__ A, const u16* __restrict__ Bt,
    u16* __restrict__ Qb, u16* __restrict__ Kb, u16* __restrict__ Vb,
    float* __restrict__ Out, int Mtot)
{
  // smem: staging lA(8KB)+lB(8KB) during K-loop; reused as C-tile in epilogue.
  __shared__ __align__(16) char smem[EPI==0 ? 34816 : 36864];
  u16* lA = (u16*)smem;              // [128][32] bf16
  u16* lB = (u16*)(smem + 8192);     // [128][32] bf16
  const int tid = threadIdx.x, lane = tid & 63, wv = tid >> 6;

  // XCD-aware bijective swizzle: each XCD gets a contiguous row-band (x-fastest).
  const int nwg = gridDim.x, chunk = nwg >> 3, orig = blockIdx.x;
  const int wg = (orig & 7)*chunk + (orig >> 3);
  int bx, by;
  if constexpr(EPI==0){ by = wg/24; bx = wg - by*24; }
  else               { by = wg>>3; bx = wg&7; }

  const int m0 = by<<7, n0 = bx<<7;
  const int wm = (wv>>1)<<6, wn = (wv&1)<<6;
  f32x4 acc[4][4];
  for(int i=0;i<4;++i) for(int j=0;j<4;++j) acc[i][j] = (f32x4){0.f,0.f,0.f,0.f};

  for(int kt=0; kt<32; ++kt){
    const int k0 = kt<<5;
    __syncthreads();
    for(int cc=0; cc<4; ++cc){
      int c = (wv<<2) + cc;                 // 0..15
      int row = ((c&7)<<4) + (lane>>2);
      int slot = lane & 3;
      if(c < 8){
        int gr = m0 + row; if(gr >= Mtot) gr = Mtot-1;
        gl_lds16(A + (size_t)gr*1024 + k0 + (slot<<3), lA + (c<<9));
      } else {
        int gr = n0 + row;
        gl_lds16(Bt + (size_t)gr*1024 + k0 + (slot<<3), lB + ((c-8)<<9));
      }
    }
    __syncthreads();
    short8 af[4], bfr[4];
    for(int i=0;i<4;++i){
      int r  = wm + (i<<4) + (lane&15);
      af[i]  = *(const short8*)&lA[(r<<5) + ((lane>>4)<<3)];
      int cn = wn + (i<<4) + (lane&15);
      bfr[i] = *(const short8*)&lB[(cn<<5) + ((lane>>4)<<3)];
    }
    for(int i=0;i<4;++i)
      for(int j=0;j<4;++j)
        acc[i][j] = __builtin_amdgcn_mfma_f32_16x16x32_bf16(af[i], bfr[j], acc[i][j], 0,0,0);
  }

  if constexpr(EPI==0){
    // block's 128 cols sit inside one of {Q,K,V} and span exactly 2 heads
    const int which = n0 >> 10;
    const int hbase = (n0 & 1023) >> 6;
    const float sc = (which==0) ? 0.125f : 1.0f;
    u16* dst = (which==0)?Qb:((which==1)?Kb:Vb);
    u16* lC = (u16*)smem;              // [128][136] bf16, 34816 B
    __syncthreads();                   // staging bufs dead
    for(int i=0;i<4;++i){
      int rb = wm + (i<<4) + ((lane>>4)<<2);
      for(int j=0;j<4;++j){
        int cc = wn + (j<<4) + (lane&15);
        for(int r=0;r<4;++r) lC[(rb+r)*136 + cc] = f2bf(acc[i][j][r]*sc);
      }
    }
    __syncthreads();
    for(int it=0; it<8; ++it){
      int idx = it*256 + tid;          // 0..2047
      int row = idx >> 4;              // 0..127
      int half = (idx >> 3) & 1;       // head within block
      int slot = idx & 7;
      int mm = m0 + row;
      if(mm < Mtot){
        int b = mm / NTOK, tok = mm - b*NTOK;
        u16x8 v = *(const u16x8*)&lC[row*136 + half*64 + slot*8];
        *(u16x8*)(dst + (((size_t)(b*NHEAD + hbase + half)*NTOK + tok)<<6) + slot*8) = v;
      }
    }
  } else {
    float* lF = (float*)smem;          // [128][72] fp32, 36864 B
    __syncthreads();
    for(int p=0;p<2;++p){
      if((wv&1)==p){
        for(int i=0;i<4;++i){
          int rb = wm + (i<<4) + ((lane>>4)<<2);
          for(int j=0;j<4;++j){
            int cc = (j<<4) + (lane&15);
            for(int r=0;r<4;++r) lF[(rb+r)*72 + cc] = acc[i][j][r];
          }
        }
      }
      __syncthreads();
      for(int it=0; it<8; ++it){
        int idx = it*256 + tid;
        int row = idx >> 4;
        int slot = idx & 15;
        int mm = m0 + row;
        if(mm < Mtot){
          float4v v = *(const float4v*)&lF[row*72 + slot*4];
          *(float4v*)(Out + (size_t)mm*1024 + n0 + p*64 + slot*4) = v;
        }
      }
      __syncthreads();
    }
  }
}

// ---------------- cls-token attention: 64 blocks (one per b*16+h) ----------------
__global__ __launch_bounds__(256) void cls_attn_kernel(
    const u16* __restrict__ Qb, const u16* __restrict__ Kb, const u16* __restrict__ Vb,
    u16* __restrict__ Abuf)
{
  __shared__ float qs[64];
  __shared__ float rm[4], rl[4];
  __shared__ float racc[4][64];
  const int tid = threadIdx.x, lane = tid & 63, wv = tid >> 6;
  const int bh = blockIdx.x;
  const u16* Kh = Kb + (size_t)bh*NTOK*DH;
  const u16* Vh = Vb + (size_t)bh*NTOK*DH;
  if(tid < 64) qs[tid] = bf2f(Qb[(size_t)bh*NTOK*DH + tid]);   // q already *0.125
  __syncthreads();
  float m = -1e30f, lsum = 0.f, accd = 0.f;
  for(int c=0;c<13;++c){
    int j = c*256 + wv*64 + lane;
    float s = -1e30f;
    if(j < NTOK){
      const u16* kr = Kh + (size_t)j*DH;
      float dot = 0.f;
      for(int t=0;t<8;++t){
        u32x4 kv = *(const u32x4*)(kr + t*8);
        for(int w=0;w<4;++w){
          u32 word = kv[w];
          u32 ulo = word<<16, uhi = word & 0xFFFF0000u;
          float lo, hi; __builtin_memcpy(&lo,&ulo,4); __builtin_memcpy(&hi,&uhi,4);
          dot += lo*qs[t*8 + 2*w] + hi*qs[t*8 + 2*w + 1];
        }
      }
      s = dot;
    }
    float cmax = s;
    for(int off=1; off<64; off<<=1) cmax = fmaxf(cmax, __shfl_xor(cmax, off));
    float mnew = fmaxf(m, cmax);
    float p = (j < NTOK) ? __expf(s - mnew) : 0.f;
    float psum = p;
    for(int off=1; off<64; off<<=1) psum += __shfl_xor(psum, off);
    float sc = __expf(m - mnew);
    lsum = lsum*sc + psum;
    accd *= sc;
    int jb = c*256 + wv*64;
    for(int jj=0;jj<64;++jj){
      int j2 = jb + jj;
      if(j2 >= NTOK) break;
      float pj = __shfl(p, jj);
      accd += pj * bf2f(Vh[(size_t)j2*DH + lane]);
    }
    m = mnew;
  }
  if(lane==0){ rm[wv]=m; rl[wv]=lsum; }
  racc[wv][lane] = accd;
  __syncthreads();
  if(wv==0){
    float M = fmaxf(fmaxf(rm[0],rm[1]), fmaxf(rm[2],rm[3]));
    float L=0.f, Av=0.f;
    for(int wi=0; wi<4; ++wi){
      float e = __expf(rm[wi]-M);
      L += rl[wi]*e; Av += racc[wi][lane]*e;
    }
    int b = bh>>4, h = bh&15;
    Abuf[(size_t)b*NTOK*1024 + h*DH + lane] = f2bf(Av/L);   // token 0 (64 lanes = 128B line)
  }
}

// ---------------- axial attention: 1024 blocks (one per (b*16+h, frame)) ----------------
__global__ __launch_bounds__(256) void axial_attn_kernel(
    const u16* __restrict__ Qb, const u16* __restrict__ Kb, const u16* __restrict__ Vb,
    u16* __restrict__ Abuf)
{
  __shared__ u16 lV[64*232];      // V^T: lV[d][ktok]
  __shared__ u16 lP[4*16*232];    // per-wave P tile; reused as per-wave O-stage [16][72]
  const int tid = threadIdx.x, lane = tid & 63, wv = tid >> 6;
  const int bf = blockIdx.x, bh = bf >> 4, fi = bf & 15;
  const u16* Kh = Kb + (size_t)bh*NTOK*DH;
  const u16* Vh = Vb + (size_t)bh*NTOK*DH;
  const u16* Qh = Qb + (size_t)bh*NTOK*DH;

  for(int c = tid; c < 224*8; c += 256){
    int tok = c >> 3, slot = c & 7;
    u16 vals[8];
    if(tok <= 196){
      size_t row = (tok==0) ? 0 : (size_t)(fi*196 + tok)*DH;
      u16x8 v = *(const u16x8*)(Vh + row + slot*8);
      for(int e=0;e<8;++e) vals[e] = v[e];
    } else {
      for(int e=0;e<8;++e) vals[e] = 0;
    }
    for(int e=0;e<8;++e) lV[(slot*8+e)*232 + tok] = vals[e];
  }
  for(int c = tid; c < 4*16*16; c += 256){
    int w2 = c >> 8, rem = c & 255, row = rem >> 4, cc = rem & 15;
    lP[w2*(16*232) + row*232 + 208 + cc] = 0;
  }
  __syncthreads();

  u16* myP = lP + wv*(16*232);
  const int b_i = bh >> 4, h = bh & 15;

  for(int qt = wv; qt < 13; qt += 4){
    int qr = qt*16 + (lane&15);
    int qrc = qr < 196 ? qr : 195;
    size_t qrow = (size_t)(1 + fi*196 + qrc)*DH;
    short8 qa0 = *(const short8*)(Qh + qrow + ((lane>>4)<<3));
    short8 qa1 = *(const short8*)(Qh + qrow + 32 + ((lane>>4)<<3));

    f32x4 s[13];
    for(int t=0;t<13;++t){
      int tok = t*16 + (lane&15);
      int tokc = tok < 197 ? tok : 196;
      size_t krow = (tokc==0) ? 0 : (size_t)(fi*196 + tokc)*DH;
      short8 b0 = *(const short8*)(Kh + krow + ((lane>>4)<<3));
      short8 b1 = *(const short8*)(Kh + krow + 32 + ((lane>>4)<<3));
      f32x4 z = {0.f,0.f,0.f,0.f};
      z = __builtin_amdgcn_mfma_f32_16x16x32_bf16(qa0, b0, z, 0,0,0);
      z = __builtin_amdgcn_mfma_f32_16x16x32_bf16(qa1, b1, z, 0,0,0);
      s[t] = z;
    }
    int mycol = lane & 15;
    if(192 + mycol >= 197)
      for(int r=0;r<4;++r) s[12][r] = -1e30f;

    f32x4 mx = s[0];
    for(int t=1;t<13;++t) for(int r=0;r<4;++r) mx[r] = fmaxf(mx[r], s[t][r]);
    for(int off=1; off<16; off<<=1)
      for(int r=0;r<4;++r) mx[r] = fmaxf(mx[r], __shfl_xor(mx[r], off));
    f32x4 lsum = {0.f,0.f,0.f,0.f};
    for(int t=0;t<13;++t) for(int r=0;r<4;++r){
      float p = __expf(s[t][r] - mx[r]); s[t][r] = p; lsum[r] += p;
    }
    for(int off=1; off<16; off<<=1)
      for(int r=0;r<4;++r) lsum[r] += __shfl_xor(lsum[r], off);

    for(int t=0;t<13;++t){
      int tok = t*16 + mycol;
      for(int r=0;r<4;++r) myP[(((lane>>4)<<2)+r)*232 + tok] = f2bf(s[t][r]);
    }

    f32x4 o[4] = {{0.f,0.f,0.f,0.f},{0.f,0.f,0.f,0.f},{0.f,0.f,0.f,0.f},{0.f,0.f,0.f,0.f}};
    for(int t2=0;t2<7;++t2){
      short8 a = *(const short8*)&myP[(lane&15)*232 + t2*32 + ((lane>>4)<<3)];
      for(int nd=0;nd<4;++nd){
        short8 b = *(const short8*)&lV[(nd*16 + (lane&15))*232 + t2*32 + ((lane>>4)<<3)];
        o[nd] = __builtin_amdgcn_mfma_f32_16x16x32_bf16(a, b, o[nd], 0,0,0);
      }
    }

    // stage wave's 16x64 output tile into (dead) P region, then coalesced 16B stores
    for(int nd=0; nd<4; ++nd){
      int d = nd*16 + (lane&15);
      for(int r=0;r<4;++r){
        int rr = ((lane>>4)<<2) + r;
        myP[rr*72 + d] = f2bf(o[nd][r] / lsum[r]);
      }
    }
    asm volatile("s_waitcnt lgkmcnt(0)" ::: "memory");
    for(int it=0; it<2; ++it){
      int idx = it*64 + lane;          // 0..127
      int row = idx >> 3, slot = idx & 7;
      int ql = qt*16 + row;
      if(ql < 196){
        u16x8 v = *(const u16x8*)&myP[row*72 + slot*8];
        int tok = 1 + fi*196 + ql;
        *(u16x8*)(Abuf + ((size_t)b_i*NTOK + tok)*1024 + h*DH + slot*8) = v;
      }
    }
  }
}

// ---------------- launcher ----------------
extern "C" void kernel_launch(void* const* d_in, const int* in_sizes, int n_in,
                              void* d_out, int out_size, void* d_ws, size_t ws_size,
                              hipStream_t stream) {
  const float* x     = (const float*)d_in[0];
  const float* wqkv  = (const float*)d_in[1];
  const float* wout  = (const float*)d_in[2];
  float* out = (float*)d_out;
  char* ws = (char*)d_ws;

  u16* xb     = (u16*)(ws);                      // 25,698,304  [M][1024] bf16
  u16* Abuf   = xb;                              // attn output (aliases xb)
  u16* wqkvT  = (u16*)(ws + 25698304);           //  6,291,456  [3072][1024] bf16
  u16* woutT  = (u16*)(ws + 31989760);           //  2,097,152  [1024][1024] bf16
  u16* Qb     = (u16*)(ws + 34086912);           // 25,698,304  [64][3137][64] bf16 (scaled)
  u16* Kb     = (u16*)(ws + 59785216);
  u16* Vb     = (u16*)(ws + 85483520);           // end 111,181,824

  cast_bf16_kernel<<<dim3(2048), dim3(256), 0, stream>>>(x, xb, (MROWS*1024)/4);
  transpose_cast_kernel<<<dim3(96,32), dim3(32,8), 0, stream>>>(wqkv, wqkvT, 1024, 3072);
  transpose_cast_kernel<<<dim3(32,32), dim3(32,8), 0, stream>>>(wout, woutT, 1024, 1024);

  gemm_kernel<0><<<dim3(2376), dim3(256), 0, stream>>>(xb, wqkvT, Qb, Kb, Vb, nullptr, MROWS);

  cls_attn_kernel<<<dim3(64), dim3(256), 0, stream>>>(Qb, Kb, Vb, Abuf);
  axial_attn_kernel<<<dim3(1024), dim3(256), 0, stream>>>(Qb, Kb, Vb, Abuf);

  gemm_kernel<1><<<dim3(792), dim3(256), 0, stream>>>(Abuf, woutT, nullptr, nullptr, nullptr, out, MROWS);
}

// Round 3
// 235.997 us; speedup vs baseline: 5.2664x; 2.1966x over previous
//
#include <hip/hip_runtime.h>
#include <stdint.h>

typedef unsigned short u16;
typedef unsigned int u32;
typedef __attribute__((ext_vector_type(4))) float f32x4;
typedef __attribute__((ext_vector_type(4))) float float4v;
typedef __attribute__((ext_vector_type(8))) short short8;
typedef __attribute__((ext_vector_type(4))) u32 u32x4;
typedef __attribute__((ext_vector_type(4))) u16 u16x4;
typedef __attribute__((ext_vector_type(8))) u16 u16x8;

#define DEV static __device__ __forceinline__

#define NTOK 3137
#define MROWS 12548
#define NHEAD 16
#define DH 64

DEV float bf2f(u16 h){ u32 u = ((u32)h)<<16; float f; __builtin_memcpy(&f,&u,4); return f; }
DEV u16 f2bf(float f){ u32 u; __builtin_memcpy(&u,&f,4); u32 r = u + 0x7FFFu + ((u>>16)&1u); return (u16)(r>>16); }

DEV void gl_lds16(const u16* g, u16* l){
  __builtin_amdgcn_global_load_lds((const __attribute__((address_space(1))) void*)g,
                                   (__attribute__((address_space(3))) void*)l, 16, 0, 0);
}

// ---------------- cast fp32 -> bf16 (vectorized) ----------------
__global__ __launch_bounds__(256) void cast_bf16_kernel(const float* __restrict__ in,
                                                        u16* __restrict__ out, int n4){
  int i = blockIdx.x*256 + threadIdx.x;
  int stride = gridDim.x*256;
  for(; i < n4; i += stride){
    float4v v = *(const float4v*)(in + (size_t)i*4);
    u16x4 o;
    for(int e=0;e<4;++e) o[e] = f2bf(v[e]);
    *(u16x4*)(out + (size_t)i*4) = o;
  }
}

// ---------------- transpose + cast: out[c][r] = bf16(in[r][c]) ----------------
__global__ void transpose_cast_kernel(const float* __restrict__ in, u16* __restrict__ out,
                                      int R, int C){
  __shared__ float tile[32][33];
  int c0 = blockIdx.x<<5, r0 = blockIdx.y<<5;
  int tx = threadIdx.x, ty = threadIdx.y;
  for(int k=0;k<32;k+=8) tile[ty+k][tx] = in[(size_t)(r0+ty+k)*C + c0+tx];
  __syncthreads();
  for(int k=0;k<32;k+=8) out[(size_t)(c0+ty+k)*R + r0+tx] = f2bf(tile[tx][ty+k]);
}

// ---------------- GEMM: C[M][N] = A[M][1024] * Bt[N][1024]^T, bf16 MFMA ----------------
template<int EPI>
__global__ __launch_bounds__(256) void gemm_kernel(
    const u16* __restrict__ A, const u16* __restrict__ Bt,
    u16* __restrict__ Qb, u16* __restrict__ Kb, u16* __restrict__ Vb,
    float* __restrict__ Out, int Mtot)
{
  __shared__ __align__(16) char smem[EPI==0 ? 34816 : 36864];
  u16* lA = (u16*)smem;              // [128][32] bf16
  u16* lB = (u16*)(smem + 8192);     // [128][32] bf16
  const int tid = threadIdx.x, lane = tid & 63, wv = tid >> 6;

  const int nwg = gridDim.x, chunk = nwg >> 3, orig = blockIdx.x;
  const int wg = (orig & 7)*chunk + (orig >> 3);
  int bx, by;
  if constexpr(EPI==0){ by = wg/24; bx = wg - by*24; }
  else               { by = wg>>3; bx = wg&7; }

  const int m0 = by<<7, n0 = bx<<7;
  const int wm = (wv>>1)<<6, wn = (wv&1)<<6;
  f32x4 acc[4][4];
  for(int i=0;i<4;++i) for(int j=0;j<4;++j) acc[i][j] = (f32x4){0.f,0.f,0.f,0.f};

  for(int kt=0; kt<32; ++kt){
    const int k0 = kt<<5;
    __syncthreads();
    for(int cc=0; cc<4; ++cc){
      int c = (wv<<2) + cc;                 // 0..15
      int row = ((c&7)<<4) + (lane>>2);
      int slot = lane & 3;
      if(c < 8){
        int gr = m0 + row; if(gr >= Mtot) gr = Mtot-1;
        gl_lds16(A + (size_t)gr*1024 + k0 + (slot<<3), lA + (c<<9));
      } else {
        int gr = n0 + row;
        gl_lds16(Bt + (size_t)gr*1024 + k0 + (slot<<3), lB + ((c-8)<<9));
      }
    }
    __syncthreads();
    short8 af[4], bfr[4];
    for(int i=0;i<4;++i){
      int r  = wm + (i<<4) + (lane&15);
      af[i]  = *(const short8*)&lA[(r<<5) + ((lane>>4)<<3)];
      int cn = wn + (i<<4) + (lane&15);
      bfr[i] = *(const short8*)&lB[(cn<<5) + ((lane>>4)<<3)];
    }
    for(int i=0;i<4;++i)
      for(int j=0;j<4;++j)
        acc[i][j] = __builtin_amdgcn_mfma_f32_16x16x32_bf16(af[i], bfr[j], acc[i][j], 0,0,0);
  }

  if constexpr(EPI==0){
    const int which = n0 >> 10;
    const int hbase = (n0 & 1023) >> 6;
    const float sc = (which==0) ? 0.125f : 1.0f;
    u16* dst = (which==0)?Qb:((which==1)?Kb:Vb);
    u16* lC = (u16*)smem;              // [128][136] bf16
    __syncthreads();
    for(int i=0;i<4;++i){
      int rb = wm + (i<<4) + ((lane>>4)<<2);
      for(int j=0;j<4;++j){
        int cc = wn + (j<<4) + (lane&15);
        for(int r=0;r<4;++r) lC[(rb+r)*136 + cc] = f2bf(acc[i][j][r]*sc);
      }
    }
    __syncthreads();
    for(int it=0; it<8; ++it){
      int idx = it*256 + tid;          // 0..2047
      int row = idx >> 4;              // 0..127
      int half = (idx >> 3) & 1;
      int slot = idx & 7;
      int mm = m0 + row;
      if(mm < Mtot){
        int b = mm / NTOK, tok = mm - b*NTOK;
        u16x8 v = *(const u16x8*)&lC[row*136 + half*64 + slot*8];
        *(u16x8*)(dst + (((size_t)(b*NHEAD + hbase + half)*NTOK + tok)<<6) + slot*8) = v;
      }
    }
  } else {
    float* lF = (float*)smem;          // [128][72] fp32
    __syncthreads();
    for(int p=0;p<2;++p){
      if((wv&1)==p){
        for(int i=0;i<4;++i){
          int rb = wm + (i<<4) + ((lane>>4)<<2);
          for(int j=0;j<4;++j){
            int cc = (j<<4) + (lane&15);
            for(int r=0;r<4;++r) lF[(rb+r)*72 + cc] = acc[i][j][r];
          }
        }
      }
      __syncthreads();
      for(int it=0; it<8; ++it){
        int idx = it*256 + tid;
        int row = idx >> 4;
        int slot = idx & 15;
        int mm = m0 + row;
        if(mm < Mtot){
          float4v v = *(const float4v*)&lF[row*72 + slot*4];
          *(float4v*)(Out + (size_t)mm*1024 + n0 + p*64 + slot*4) = v;
        }
      }
      __syncthreads();
    }
  }
}

// ---------------- cls attention, flash-decode split-K ----------------
// partial: grid (13 chunks, 64 bh). Each block: 256 tokens; per-wave 64 tokens.
// Writes per-(bh,chunk) partial {m, l, acc[64]} fp32 (stride 68).
__global__ __launch_bounds__(256) void cls_partial_kernel(
    const u16* __restrict__ Qb, const u16* __restrict__ Kb, const u16* __restrict__ Vb,
    float* __restrict__ part)
{
  __shared__ float qs[64];
  __shared__ float pbuf[4][64];
  __shared__ float wm[4], wl[4];
  __shared__ float wacc[4][64];
  const int tid = threadIdx.x, lane = tid & 63, wv = tid >> 6;
  const int c = blockIdx.x, bh = blockIdx.y;
  const u16* Kh = Kb + (size_t)bh*NTOK*DH;
  const u16* Vh = Vb + (size_t)bh*NTOK*DH;
  if(tid < 64) qs[tid] = bf2f(Qb[(size_t)bh*NTOK*DH + tid]);   // q already *0.125
  __syncthreads();

  const int jb = c*256 + wv*64;
  const int j = jb + lane;
  float s = -1e30f;
  if(j < NTOK){
    const u16* kr = Kh + (size_t)j*DH;
    float dot = 0.f;
    for(int t=0;t<8;++t){
      u16x8 kv = *(const u16x8*)(kr + t*8);
      for(int e=0;e<8;++e) dot += bf2f(kv[e]) * qs[t*8+e];
    }
    s = dot;
  }
  float mw = s;
  for(int off=1; off<64; off<<=1) mw = fmaxf(mw, __shfl_xor(mw, off));
  float p = (j < NTOK) ? __expf(s - mw) : 0.f;
  float lw = p;
  for(int off=1; off<64; off<<=1) lw += __shfl_xor(lw, off);
  pbuf[wv][lane] = p;

  float accd = 0.f;                    // lane = d now
  if(jb < NTOK){
    int nv = NTOK - jb; if(nv > 64) nv = 64;
    for(int jj=0; jj<nv; ++jj)
      accd += pbuf[wv][jj] * bf2f(Vh[(size_t)(jb+jj)*DH + lane]);
  }
  wacc[wv][lane] = accd;
  if(lane==0){ wm[wv]=mw; wl[wv]=lw; }
  __syncthreads();
  if(wv==0){
    float M = fmaxf(fmaxf(wm[0],wm[1]), fmaxf(wm[2],wm[3]));
    float L=0.f, A=0.f;
    for(int wi=0; wi<4; ++wi){
      float e = __expf(wm[wi]-M);
      L += wl[wi]*e; A += wacc[wi][lane]*e;
    }
    float* dst = part + ((size_t)bh*13 + c)*68;
    if(lane==0){ dst[0]=M; dst[1]=L; }
    dst[2+lane] = A;
  }
}

__global__ __launch_bounds__(64) void cls_reduce_kernel(
    const float* __restrict__ part, u16* __restrict__ Abuf)
{
  const int lane = threadIdx.x, bh = blockIdx.x;
  const float* p0 = part + (size_t)bh*13*68;
  float M = -1e30f;
  for(int i=0;i<13;++i) M = fmaxf(M, p0[i*68]);
  float L=0.f, A=0.f;
  for(int i=0;i<13;++i){
    float e = __expf(p0[i*68] - M);
    L += p0[i*68+1]*e;
    A += p0[i*68+2+lane]*e;
  }
  int b = bh>>4, h = bh&15;
  Abuf[(size_t)b*NTOK*1024 + h*DH + lane] = f2bf(A/L);   // token 0, 128B line
}

// ---------------- axial attention: 1024 blocks (one per (b*16+h, frame)) ----------------
__global__ __launch_bounds__(256) void axial_attn_kernel(
    const u16* __restrict__ Qb, const u16* __restrict__ Kb, const u16* __restrict__ Vb,
    u16* __restrict__ Abuf)
{
  __shared__ u16 lV[64*232];      // V^T: lV[d][ktok]
  __shared__ u16 lP[4*16*232];    // per-wave P tile; reused as per-wave O-stage [16][72]
  const int tid = threadIdx.x, lane = tid & 63, wv = tid >> 6;
  const int bf = blockIdx.x, bh = bf >> 4, fi = bf & 15;
  const u16* Kh = Kb + (size_t)bh*NTOK*DH;
  const u16* Vh = Vb + (size_t)bh*NTOK*DH;
  const u16* Qh = Qb + (size_t)bh*NTOK*DH;

  for(int c = tid; c < 224*8; c += 256){
    int tok = c >> 3, slot = c & 7;
    u16 vals[8];
    if(tok <= 196){
      size_t row = (tok==0) ? 0 : (size_t)(fi*196 + tok)*DH;
      u16x8 v = *(const u16x8*)(Vh + row + slot*8);
      for(int e=0;e<8;++e) vals[e] = v[e];
    } else {
      for(int e=0;e<8;++e) vals[e] = 0;
    }
    for(int e=0;e<8;++e) lV[(slot*8+e)*232 + tok] = vals[e];
  }
  for(int c = tid; c < 4*16*16; c += 256){
    int w2 = c >> 8, rem = c & 255, row = rem >> 4, cc = rem & 15;
    lP[w2*(16*232) + row*232 + 208 + cc] = 0;
  }
  __syncthreads();

  u16* myP = lP + wv*(16*232);
  const int b_i = bh >> 4, h = bh & 15;

  for(int qt = wv; qt < 13; qt += 4){
    int qr = qt*16 + (lane&15);
    int qrc = qr < 196 ? qr : 195;
    size_t qrow = (size_t)(1 + fi*196 + qrc)*DH;
    short8 qa0 = *(const short8*)(Qh + qrow + ((lane>>4)<<3));
    short8 qa1 = *(const short8*)(Qh + qrow + 32 + ((lane>>4)<<3));

    f32x4 s[13];
    for(int t=0;t<13;++t){
      int tok = t*16 + (lane&15);
      int tokc = tok < 197 ? tok : 196;
      size_t krow = (tokc==0) ? 0 : (size_t)(fi*196 + tokc)*DH;
      short8 b0 = *(const short8*)(Kh + krow + ((lane>>4)<<3));
      short8 b1 = *(const short8*)(Kh + krow + 32 + ((lane>>4)<<3));
      f32x4 z = {0.f,0.f,0.f,0.f};
      z = __builtin_amdgcn_mfma_f32_16x16x32_bf16(qa0, b0, z, 0,0,0);
      z = __builtin_amdgcn_mfma_f32_16x16x32_bf16(qa1, b1, z, 0,0,0);
      s[t] = z;
    }
    int mycol = lane & 15;
    if(192 + mycol >= 197)
      for(int r=0;r<4;++r) s[12][r] = -1e30f;

    f32x4 mx = s[0];
    for(int t=1;t<13;++t) for(int r=0;r<4;++r) mx[r] = fmaxf(mx[r], s[t][r]);
    for(int off=1; off<16; off<<=1)
      for(int r=0;r<4;++r) mx[r] = fmaxf(mx[r], __shfl_xor(mx[r], off));
    f32x4 lsum = {0.f,0.f,0.f,0.f};
    for(int t=0;t<13;++t) for(int r=0;r<4;++r){
      float p = __expf(s[t][r] - mx[r]); s[t][r] = p; lsum[r] += p;
    }
    for(int off=1; off<16; off<<=1)
      for(int r=0;r<4;++r) lsum[r] += __shfl_xor(lsum[r], off);

    for(int t=0;t<13;++t){
      int tok = t*16 + mycol;
      for(int r=0;r<4;++r) myP[(((lane>>4)<<2)+r)*232 + tok] = f2bf(s[t][r]);
    }

    f32x4 o[4] = {{0.f,0.f,0.f,0.f},{0.f,0.f,0.f,0.f},{0.f,0.f,0.f,0.f},{0.f,0.f,0.f,0.f}};
    for(int t2=0;t2<7;++t2){
      short8 a = *(const short8*)&myP[(lane&15)*232 + t2*32 + ((lane>>4)<<3)];
      for(int nd=0;nd<4;++nd){
        short8 b = *(const short8*)&lV[(nd*16 + (lane&15))*232 + t2*32 + ((lane>>4)<<3)];
        o[nd] = __builtin_amdgcn_mfma_f32_16x16x32_bf16(a, b, o[nd], 0,0,0);
      }
    }

    for(int nd=0; nd<4; ++nd){
      int d = nd*16 + (lane&15);
      for(int r=0;r<4;++r){
        int rr = ((lane>>4)<<2) + r;
        myP[rr*72 + d] = f2bf(o[nd][r] / lsum[r]);
      }
    }
    asm volatile("s_waitcnt lgkmcnt(0)" ::: "memory");
    for(int it=0; it<2; ++it){
      int idx = it*64 + lane;          // 0..127
      int row = idx >> 3, slot = idx & 7;
      int ql = qt*16 + row;
      if(ql < 196){
        u16x8 v = *(const u16x8*)&myP[row*72 + slot*8];
        int tok = 1 + fi*196 + ql;
        *(u16x8*)(Abuf + ((size_t)b_i*NTOK + tok)*1024 + h*DH + slot*8) = v;
      }
    }
  }
}

// ---------------- launcher ----------------
extern "C" void kernel_launch(void* const* d_in, const int* in_sizes, int n_in,
                              void* d_out, int out_size, void* d_ws, size_t ws_size,
                              hipStream_t stream) {
  const float* x     = (const float*)d_in[0];
  const float* wqkv  = (const float*)d_in[1];
  const float* wout  = (const float*)d_in[2];
  float* out = (float*)d_out;
  char* ws = (char*)d_ws;

  u16* xb     = (u16*)(ws);                      // 25,698,304  [M][1024] bf16
  u16* Abuf   = xb;                              // attn output (aliases xb)
  u16* wqkvT  = (u16*)(ws + 25698304);           //  6,291,456  [3072][1024] bf16
  float* clsPart = (float*)(ws + 25698304);      // aliases wqkvT (dead after gemm<0>): 64*13*68*4 B
  u16* woutT  = (u16*)(ws + 31989760);           //  2,097,152  [1024][1024] bf16
  u16* Qb     = (u16*)(ws + 34086912);           // 25,698,304  [64][3137][64] bf16 (scaled)
  u16* Kb     = (u16*)(ws + 59785216);
  u16* Vb     = (u16*)(ws + 85483520);           // end 111,181,824

  cast_bf16_kernel<<<dim3(2048), dim3(256), 0, stream>>>(x, xb, (MROWS*1024)/4);
  transpose_cast_kernel<<<dim3(96,32), dim3(32,8), 0, stream>>>(wqkv, wqkvT, 1024, 3072);
  transpose_cast_kernel<<<dim3(32,32), dim3(32,8), 0, stream>>>(wout, woutT, 1024, 1024);

  gemm_kernel<0><<<dim3(2376), dim3(256), 0, stream>>>(xb, wqkvT, Qb, Kb, Vb, nullptr, MROWS);

  cls_partial_kernel<<<dim3(13,64), dim3(256), 0, stream>>>(Qb, Kb, Vb, clsPart);
  cls_reduce_kernel<<<dim3(64), dim3(64), 0, stream>>>(clsPart, Abuf);
  axial_attn_kernel<<<dim3(1024), dim3(256), 0, stream>>>(Qb, Kb, Vb, Abuf);

  gemm_kernel<1><<<dim3(792), dim3(256), 0, stream>>>(Abuf, woutT, nullptr, nullptr, nullptr, out, MROWS);
}

// Round 4
// 218.693 us; speedup vs baseline: 5.6832x; 1.0791x over previous
//
#include <hip/hip_runtime.h>
#include <stdint.h>

typedef unsigned short u16;
typedef unsigned int u32;
typedef __attribute__((ext_vector_type(4))) float f32x4;
typedef __attribute__((ext_vector_type(4))) float float4v;
typedef __attribute__((ext_vector_type(8))) short short8;
typedef __attribute__((ext_vector_type(4))) u32 u32x4;
typedef __attribute__((ext_vector_type(4))) u16 u16x4;
typedef __attribute__((ext_vector_type(8))) u16 u16x8;

#define DEV static __device__ __forceinline__

#define NTOK 3137
#define MROWS 12548
#define NHEAD 16
#define DH 64
#define NKT 16            // K=1024 / BK=64

DEV float bf2f(u16 h){ u32 u = ((u32)h)<<16; float f; __builtin_memcpy(&f,&u,4); return f; }
DEV u16 f2bf(float f){ u32 u; __builtin_memcpy(&u,&f,4); u32 r = u + 0x7FFFu + ((u>>16)&1u); return (u16)(r>>16); }

DEV void gl_lds16(const u16* g, u16* l){
  __builtin_amdgcn_global_load_lds((const __attribute__((address_space(1))) void*)g,
                                   (__attribute__((address_space(3))) void*)l, 16, 0, 0);
}

#define BARRIER()  asm volatile("s_barrier" ::: "memory")
#define WAIT_LGKM0() asm volatile("s_waitcnt lgkmcnt(0)" ::: "memory")
#define WAIT_VM(n)  asm volatile("s_waitcnt vmcnt(" #n ")" ::: "memory")

// ---------------- cast fp32 -> bf16 (vectorized) ----------------
__global__ __launch_bounds__(256) void cast_bf16_kernel(const float* __restrict__ in,
                                                        u16* __restrict__ out, int n4){
  int i = blockIdx.x*256 + threadIdx.x;
  int stride = gridDim.x*256;
  for(; i < n4; i += stride){
    float4v v = *(const float4v*)(in + (size_t)i*4);
    u16x4 o;
    for(int e=0;e<4;++e) o[e] = f2bf(v[e]);
    *(u16x4*)(out + (size_t)i*4) = o;
  }
}

// ---------------- transpose + cast: out[c][r] = bf16(in[r][c]) ----------------
__global__ void transpose_cast_kernel(const float* __restrict__ in, u16* __restrict__ out,
                                      int R, int C){
  __shared__ float tile[32][33];
  int c0 = blockIdx.x<<5, r0 = blockIdx.y<<5;
  int tx = threadIdx.x, ty = threadIdx.y;
  for(int k=0;k<32;k+=8) tile[ty+k][tx] = in[(size_t)(r0+ty+k)*C + c0+tx];
  __syncthreads();
  for(int k=0;k<32;k+=8) out[(size_t)(c0+ty+k)*R + r0+tx] = f2bf(tile[tx][ty+k]);
}

// ---------------- 256x256 8-phase GEMM: C[M][N] = A[M][1024] * Bt[N][1024]^T ----------------
// 512 threads = 8 waves (2M x 4N). BK=64, double-buffered LDS (128 KiB), swizzled.
// EPI==0: Q(*0.125)/K/V scatter bf16.  EPI==1: fp32 Out.
template<int EPI>
__global__ __launch_bounds__(512, 2) void gemm256_kernel(
    const u16* __restrict__ A, const u16* __restrict__ Bt,
    u16* __restrict__ Qb, u16* __restrict__ Kb, u16* __restrict__ Vb,
    float* __restrict__ Out, int Mtot, int tilesx)
{
  __shared__ __align__(16) char smem[131072];
  const int tid = threadIdx.x, lane = tid & 63, wid = tid >> 6;
  const int wr = wid >> 2, wc = wid & 3;

  // XCD-aware bijective swizzle (grid % 8 == 0)
  const int nwg = gridDim.x, chunk = nwg >> 3, orig = blockIdx.x;
  const int wg = (orig & 7)*chunk + (orig >> 3);
  const int by = wg / tilesx, bx = wg - by*tilesx;
  const int m0 = by << 8, n0 = bx << 8;

  f32x4 acc[8][4];
  #pragma unroll
  for(int i=0;i<8;++i)
    #pragma unroll
    for(int j=0;j<4;++j) acc[i][j] = (f32x4){0.f,0.f,0.f,0.f};

  // stage half-tile hi (0,1 = A halves rows 0-127/128-255; 2,3 = B halves) of K-tile t
  auto STAGE = [&](int t, int hi){
    const int bsel = t & 1;
    char* base = smem + bsel*65536 + ((hi>>1)<<15) + ((hi&1)<<14);
    const u16* mat = (hi < 2) ? A : Bt;
    const int rbase = ((hi < 2) ? m0 : n0) + ((hi&1)<<7);
    #pragma unroll
    for(int j=0;j<2;++j){
      int idx = j*512 + tid;
      int r = idx >> 3;
      int c2s = ((idx&7)<<4) ^ ((r&7)<<4);     // pre-swizzled source col (involution)
      int grow = rbase + r;
      if(hi < 2 && grow >= Mtot) grow = Mtot - 1;
      const u16* src = mat + (size_t)grow*1024 + t*64 + (c2s>>1);
      u16* dst = (u16*)(base + j*8192 + wid*1024);   // wave-uniform; HW adds lane*16
      gl_lds16(src, dst);
    }
  };

  const int rA   = (lane&15)*128;
  const int csw0 = (((lane>>4)<<4)      ) ^ ((lane&7)<<4);
  const int csw1 = (((lane>>4)<<4) + 64 ) ^ ((lane&7)<<4);

  auto RDA = [&](int bsel, int i, int kk)->short8 {
    const char* p = smem + bsel*65536 + (wr<<14) + (i<<4)*128 + rA + (kk ? csw1 : csw0);
    return *(const short8*)p;
  };
  auto RDB = [&](int bsel, int jn, int kk)->short8 {
    const char* p = smem + bsel*65536 + 32768 + ((wc>>1)<<14)
                  + (((wc&1)<<6) + (jn<<4))*128 + rA + (kk ? csw1 : csw0);
    return *(const short8*)p;
  };

  // prologue: K-tile 0 fully + K-tile 1 half0
  STAGE(0,0); STAGE(0,1); STAGE(0,2); STAGE(0,3); STAGE(1,0);
  WAIT_VM(2);
  BARRIER();

  short8 aR[4][2], b0[2][2], b1[2][2];
  for(int t=0; t<NKT; ++t){
    const int bs = t & 1;
    // ---- P1: read A rows 0-63 + B cols 0-31; stage next H1; MFMA q(r0,c0)
    #pragma unroll
    for(int i=0;i<4;++i){ aR[i][0]=RDA(bs,i,0); aR[i][1]=RDA(bs,i,1); }
    #pragma unroll
    for(int j=0;j<2;++j){ b0[j][0]=RDB(bs,j,0); b0[j][1]=RDB(bs,j,1); }
    if(t+1<NKT) STAGE(t+1,1);
    BARRIER(); WAIT_LGKM0();
    __builtin_amdgcn_s_setprio(1);
    #pragma unroll
    for(int i=0;i<4;++i)
      #pragma unroll
      for(int j=0;j<2;++j){
        acc[i][j] = __builtin_amdgcn_mfma_f32_16x16x32_bf16(aR[i][0], b0[j][0], acc[i][j], 0,0,0);
        acc[i][j] = __builtin_amdgcn_mfma_f32_16x16x32_bf16(aR[i][1], b0[j][1], acc[i][j], 0,0,0);
      }
    __builtin_amdgcn_s_setprio(0);
    BARRIER();
    // ---- P2: read B cols 32-63; stage next H2; MFMA q(r0,c1)
    #pragma unroll
    for(int j=0;j<2;++j){ b1[j][0]=RDB(bs,2+j,0); b1[j][1]=RDB(bs,2+j,1); }
    if(t+1<NKT) STAGE(t+1,2);
    BARRIER(); WAIT_LGKM0();
    __builtin_amdgcn_s_setprio(1);
    #pragma unroll
    for(int i=0;i<4;++i)
      #pragma unroll
      for(int j=0;j<2;++j){
        acc[i][2+j] = __builtin_amdgcn_mfma_f32_16x16x32_bf16(aR[i][0], b1[j][0], acc[i][2+j], 0,0,0);
        acc[i][2+j] = __builtin_amdgcn_mfma_f32_16x16x32_bf16(aR[i][1], b1[j][1], acc[i][2+j], 0,0,0);
      }
    __builtin_amdgcn_s_setprio(0);
    BARRIER();
    // ---- P3: read A rows 64-127; stage next H3; MFMA q(r1,c1)
    #pragma unroll
    for(int i=0;i<4;++i){ aR[i][0]=RDA(bs,4+i,0); aR[i][1]=RDA(bs,4+i,1); }
    if(t+1<NKT) STAGE(t+1,3);
    BARRIER(); WAIT_LGKM0();
    __builtin_amdgcn_s_setprio(1);
    #pragma unroll
    for(int i=0;i<4;++i)
      #pragma unroll
      for(int j=0;j<2;++j){
        acc[4+i][2+j] = __builtin_amdgcn_mfma_f32_16x16x32_bf16(aR[i][0], b1[j][0], acc[4+i][2+j], 0,0,0);
        acc[4+i][2+j] = __builtin_amdgcn_mfma_f32_16x16x32_bf16(aR[i][1], b1[j][1], acc[4+i][2+j], 0,0,0);
      }
    __builtin_amdgcn_s_setprio(0);
    BARRIER();
    // ---- P4: stage t+2 H0 (into current buf; H0 reads done at P3); counted vmcnt; MFMA q(r1,c0)
    if(t+2<NKT) STAGE(t+2,0);
    if(t < NKT-2){ WAIT_VM(2); } else { WAIT_VM(0); }
    BARRIER();
    __builtin_amdgcn_s_setprio(1);
    #pragma unroll
    for(int i=0;i<4;++i)
      #pragma unroll
      for(int j=0;j<2;++j){
        acc[4+i][j] = __builtin_amdgcn_mfma_f32_16x16x32_bf16(aR[i][0], b0[j][0], acc[4+i][j], 0,0,0);
        acc[4+i][j] = __builtin_amdgcn_mfma_f32_16x16x32_bf16(aR[i][1], b0[j][1], acc[4+i][j], 0,0,0);
      }
    __builtin_amdgcn_s_setprio(0);
    BARRIER();
  }

  __syncthreads();

  if constexpr(EPI==0){
    const int which = n0 >> 10;                 // 256-tile always inside one of Q/K/V
    const int hbase = (n0 & 1023) >> 6;         // 4 heads per tile
    const float sc = (which==0) ? 0.125f : 1.0f;
    u16* dst = (which==0)?Qb:((which==1)?Kb:Vb);
    u16* lC = (u16*)smem;                       // [128][264] bf16 per row-half phase
    for(int rh=0; rh<2; ++rh){
      if(wr == rh){
        #pragma unroll
        for(int i=0;i<8;++i){
          int rr = (i<<4) + ((lane>>4)<<2);
          #pragma unroll
          for(int j=0;j<4;++j){
            int ct = (wc<<6) + (j<<4) + (lane&15);
            #pragma unroll
            for(int r=0;r<4;++r) lC[(rr+r)*264 + ct] = f2bf(acc[i][j][r]*sc);
          }
        }
      }
      __syncthreads();
      for(int it=0; it<8; ++it){
        int idx = it*512 + tid;                 // 0..4095
        int row = idx >> 5, rest = idx & 31, hh = rest>>3, slot = rest&7;
        int mm = m0 + rh*128 + row;
        if(mm < Mtot){
          int b = mm / NTOK, tok = mm - b*NTOK;
          u16x8 v = *(const u16x8*)&lC[row*264 + hh*64 + slot*8];
          *(u16x8*)(dst + (((size_t)(b*NHEAD + hbase + hh)*NTOK + tok)<<6) + slot*8) = v;
        }
      }
      __syncthreads();
    }
  } else {
    float* lF = (float*)smem;                   // [128][132] fp32 per (row-half, col-half)
    for(int ph=0; ph<4; ++ph){
      int rh = ph>>1, ch = ph&1;
      if(wr==rh && (wc>>1)==ch){
        #pragma unroll
        for(int i=0;i<8;++i){
          int rr = (i<<4) + ((lane>>4)<<2);
          #pragma unroll
          for(int j=0;j<4;++j){
            int ct = ((wc&1)<<6) + (j<<4) + (lane&15);
            #pragma unroll
            for(int r=0;r<4;++r) lF[(rr+r)*132 + ct] = acc[i][j][r];
          }
        }
      }
      __syncthreads();
      for(int it=0; it<8; ++it){
        int idx = it*512 + tid;
        int row = idx >> 5, slot = idx & 31;
        int mm = m0 + rh*128 + row;
        if(mm < Mtot){
          float4v v = *(const float4v*)&lF[row*132 + slot*4];
          *(float4v*)(Out + (size_t)mm*1024 + n0 + ch*128 + slot*4) = v;
        }
      }
      __syncthreads();
    }
  }
}

// ---------------- cls attention, flash-decode split-K ----------------
__global__ __launch_bounds__(256) void cls_partial_kernel(
    const u16* __restrict__ Qb, const u16* __restrict__ Kb, const u16* __restrict__ Vb,
    float* __restrict__ part)
{
  __shared__ float qs[64];
  __shared__ float pbuf[4][64];
  __shared__ float wm[4], wl[4];
  __shared__ float wacc[4][64];
  const int tid = threadIdx.x, lane = tid & 63, wv = tid >> 6;
  const int c = blockIdx.x, bh = blockIdx.y;
  const u16* Kh = Kb + (size_t)bh*NTOK*DH;
  const u16* Vh = Vb + (size_t)bh*NTOK*DH;
  if(tid < 64) qs[tid] = bf2f(Qb[(size_t)bh*NTOK*DH + tid]);   // q already *0.125
  __syncthreads();

  const int jb = c*256 + wv*64;
  const int j = jb + lane;
  float s = -1e30f;
  if(j < NTOK){
    const u16* kr = Kh + (size_t)j*DH;
    float dot = 0.f;
    for(int t=0;t<8;++t){
      u16x8 kv = *(const u16x8*)(kr + t*8);
      for(int e=0;e<8;++e) dot += bf2f(kv[e]) * qs[t*8+e];
    }
    s = dot;
  }
  float mw = s;
  for(int off=1; off<64; off<<=1) mw = fmaxf(mw, __shfl_xor(mw, off));
  float p = (j < NTOK) ? __expf(s - mw) : 0.f;
  float lw = p;
  for(int off=1; off<64; off<<=1) lw += __shfl_xor(lw, off);
  pbuf[wv][lane] = p;

  float accd = 0.f;                    // lane = d now
  if(jb < NTOK){
    int nv = NTOK - jb; if(nv > 64) nv = 64;
    for(int jj=0; jj<nv; ++jj)
      accd += pbuf[wv][jj] * bf2f(Vh[(size_t)(jb+jj)*DH + lane]);
  }
  wacc[wv][lane] = accd;
  if(lane==0){ wm[wv]=mw; wl[wv]=lw; }
  __syncthreads();
  if(wv==0){
    float M = fmaxf(fmaxf(wm[0],wm[1]), fmaxf(wm[2],wm[3]));
    float L=0.f, Acc=0.f;
    for(int wi=0; wi<4; ++wi){
      float e = __expf(wm[wi]-M);
      L += wl[wi]*e; Acc += wacc[wi][lane]*e;
    }
    float* dstp = part + ((size_t)bh*13 + c)*68;
    if(lane==0){ dstp[0]=M; dstp[1]=L; }
    dstp[2+lane] = Acc;
  }
}

__global__ __launch_bounds__(64) void cls_reduce_kernel(
    const float* __restrict__ part, u16* __restrict__ Abuf)
{
  const int lane = threadIdx.x, bh = blockIdx.x;
  const float* p0 = part + (size_t)bh*13*68;
  float M = -1e30f;
  for(int i=0;i<13;++i) M = fmaxf(M, p0[i*68]);
  float L=0.f, Acc=0.f;
  for(int i=0;i<13;++i){
    float e = __expf(p0[i*68] - M);
    L += p0[i*68+1]*e;
    Acc += p0[i*68+2+lane]*e;
  }
  int b = bh>>4, h = bh&15;
  Abuf[(size_t)b*NTOK*1024 + h*DH + lane] = f2bf(Acc/L);   // token 0, 128B line
}

// ---------------- axial attention: 1024 blocks (one per (b*16+h, frame)) ----------------
__global__ __launch_bounds__(256) void axial_attn_kernel(
    const u16* __restrict__ Qb, const u16* __restrict__ Kb, const u16* __restrict__ Vb,
    u16* __restrict__ Abuf)
{
  __shared__ u16 lV[64*232];      // V^T: lV[d][ktok]
  __shared__ u16 lP[4*16*232];    // per-wave P tile; reused as per-wave O-stage [16][72]
  const int tid = threadIdx.x, lane = tid & 63, wv = tid >> 6;
  const int bf = blockIdx.x, bh = bf >> 4, fi = bf & 15;
  const u16* Kh = Kb + (size_t)bh*NTOK*DH;
  const u16* Vh = Vb + (size_t)bh*NTOK*DH;
  const u16* Qh = Qb + (size_t)bh*NTOK*DH;

  for(int c = tid; c < 224*8; c += 256){
    int tok = c >> 3, slot = c & 7;
    u16 vals[8];
    if(tok <= 196){
      size_t row = (tok==0) ? 0 : (size_t)(fi*196 + tok)*DH;
      u16x8 v = *(const u16x8*)(Vh + row + slot*8);
      for(int e=0;e<8;++e) vals[e] = v[e];
    } else {
      for(int e=0;e<8;++e) vals[e] = 0;
    }
    for(int e=0;e<8;++e) lV[(slot*8+e)*232 + tok] = vals[e];
  }
  for(int c = tid; c < 4*16*16; c += 256){
    int w2 = c >> 8, rem = c & 255, row = rem >> 4, cc = rem & 15;
    lP[w2*(16*232) + row*232 + 208 + cc] = 0;
  }
  __syncthreads();

  u16* myP = lP + wv*(16*232);
  const int b_i = bh >> 4, h = bh & 15;

  for(int qt = wv; qt < 13; qt += 4){
    int qr = qt*16 + (lane&15);
    int qrc = qr < 196 ? qr : 195;
    size_t qrow = (size_t)(1 + fi*196 + qrc)*DH;
    short8 qa0 = *(const short8*)(Qh + qrow + ((lane>>4)<<3));
    short8 qa1 = *(const short8*)(Qh + qrow + 32 + ((lane>>4)<<3));

    f32x4 s[13];
    for(int t=0;t<13;++t){
      int tok = t*16 + (lane&15);
      int tokc = tok < 197 ? tok : 196;
      size_t krow = (tokc==0) ? 0 : (size_t)(fi*196 + tokc)*DH;
      short8 b0v = *(const short8*)(Kh + krow + ((lane>>4)<<3));
      short8 b1v = *(const short8*)(Kh + krow + 32 + ((lane>>4)<<3));
      f32x4 z = {0.f,0.f,0.f,0.f};
      z = __builtin_amdgcn_mfma_f32_16x16x32_bf16(qa0, b0v, z, 0,0,0);
      z = __builtin_amdgcn_mfma_f32_16x16x32_bf16(qa1, b1v, z, 0,0,0);
      s[t] = z;
    }
    int mycol = lane & 15;
    if(192 + mycol >= 197)
      for(int r=0;r<4;++r) s[12][r] = -1e30f;

    f32x4 mx = s[0];
    for(int t=1;t<13;++t) for(int r=0;r<4;++r) mx[r] = fmaxf(mx[r], s[t][r]);
    for(int off=1; off<16; off<<=1)
      for(int r=0;r<4;++r) mx[r] = fmaxf(mx[r], __shfl_xor(mx[r], off));
    f32x4 lsum = {0.f,0.f,0.f,0.f};
    for(int t=0;t<13;++t) for(int r=0;r<4;++r){
      float p = __expf(s[t][r] - mx[r]); s[t][r] = p; lsum[r] += p;
    }
    for(int off=1; off<16; off<<=1)
      for(int r=0;r<4;++r) lsum[r] += __shfl_xor(lsum[r], off);

    for(int t=0;t<13;++t){
      int tok = t*16 + mycol;
      for(int r=0;r<4;++r) myP[(((lane>>4)<<2)+r)*232 + tok] = f2bf(s[t][r]);
    }

    f32x4 o[4] = {{0.f,0.f,0.f,0.f},{0.f,0.f,0.f,0.f},{0.f,0.f,0.f,0.f},{0.f,0.f,0.f,0.f}};
    for(int t2=0;t2<7;++t2){
      short8 a = *(const short8*)&myP[(lane&15)*232 + t2*32 + ((lane>>4)<<3)];
      for(int nd=0;nd<4;++nd){
        short8 b = *(const short8*)&lV[(nd*16 + (lane&15))*232 + t2*32 + ((lane>>4)<<3)];
        o[nd] = __builtin_amdgcn_mfma_f32_16x16x32_bf16(a, b, o[nd], 0,0,0);
      }
    }

    for(int nd=0; nd<4; ++nd){
      int d = nd*16 + (lane&15);
      for(int r=0;r<4;++r){
        int rr = ((lane>>4)<<2) + r;
        myP[rr*72 + d] = f2bf(o[nd][r] / lsum[r]);
      }
    }
    asm volatile("s_waitcnt lgkmcnt(0)" ::: "memory");
    for(int it=0; it<2; ++it){
      int idx = it*64 + lane;          // 0..127
      int row = idx >> 3, slot = idx & 7;
      int ql = qt*16 + row;
      if(ql < 196){
        u16x8 v = *(const u16x8*)&myP[row*72 + slot*8];
        int tok = 1 + fi*196 + ql;
        *(u16x8*)(Abuf + ((size_t)b_i*NTOK + tok)*1024 + h*DH + slot*8) = v;
      }
    }
  }
}

// ---------------- launcher ----------------
extern "C" void kernel_launch(void* const* d_in, const int* in_sizes, int n_in,
                              void* d_out, int out_size, void* d_ws, size_t ws_size,
                              hipStream_t stream) {
  const float* x     = (const float*)d_in[0];
  const float* wqkv  = (const float*)d_in[1];
  const float* wout  = (const float*)d_in[2];
  float* out = (float*)d_out;
  char* ws = (char*)d_ws;

  u16* xb     = (u16*)(ws);                      // 25,698,304  [M][1024] bf16
  u16* Abuf   = xb;                              // attn output (aliases xb)
  u16* wqkvT  = (u16*)(ws + 25698304);           //  6,291,456  [3072][1024] bf16
  float* clsPart = (float*)(ws + 25698304);      // aliases wqkvT (dead after gemm<0>)
  u16* woutT  = (u16*)(ws + 31989760);           //  2,097,152  [1024][1024] bf16
  u16* Qb     = (u16*)(ws + 34086912);           // 25,698,304  [64][3137][64] bf16 (scaled)
  u16* Kb     = (u16*)(ws + 59785216);
  u16* Vb     = (u16*)(ws + 85483520);           // end 111,181,824

  cast_bf16_kernel<<<dim3(2048), dim3(256), 0, stream>>>(x, xb, (MROWS*1024)/4);
  transpose_cast_kernel<<<dim3(96,32), dim3(32,8), 0, stream>>>(wqkv, wqkvT, 1024, 3072);
  transpose_cast_kernel<<<dim3(32,32), dim3(32,8), 0, stream>>>(wout, woutT, 1024, 1024);

  // M-tiles = ceil(12548/256) = 50; gemm<0>: 50x12 = 600 blocks; gemm<1>: 50x4 = 200
  gemm256_kernel<0><<<dim3(600), dim3(512), 0, stream>>>(xb, wqkvT, Qb, Kb, Vb, nullptr, MROWS, 12);

  cls_partial_kernel<<<dim3(13,64), dim3(256), 0, stream>>>(Qb, Kb, Vb, clsPart);
  cls_reduce_kernel<<<dim3(64), dim3(64), 0, stream>>>(clsPart, Abuf);
  axial_attn_kernel<<<dim3(1024), dim3(256), 0, stream>>>(Qb, Kb, Vb, Abuf);

  gemm256_kernel<1><<<dim3(200), dim3(512), 0, stream>>>(Abuf, woutT, nullptr, nullptr, nullptr, out, MROWS, 4);
}

// Round 5
// 212.753 us; speedup vs baseline: 5.8418x; 1.0279x over previous
//
#include <hip/hip_runtime.h>
#include <stdint.h>

typedef unsigned short u16;
typedef unsigned int u32;
typedef __attribute__((ext_vector_type(4))) float f32x4;
typedef __attribute__((ext_vector_type(4))) float float4v;
typedef __attribute__((ext_vector_type(8))) short short8;
typedef __attribute__((ext_vector_type(4))) u32 u32x4;
typedef __attribute__((ext_vector_type(4))) u16 u16x4;
typedef __attribute__((ext_vector_type(8))) u16 u16x8;

#define DEV static __device__ __forceinline__

#define NTOK 3137
#define MROWS 12548
#define NHEAD 16
#define DH 64
#define NKT 16            // K=1024 / BK=64

DEV float bf2f(u16 h){ u32 u = ((u32)h)<<16; float f; __builtin_memcpy(&f,&u,4); return f; }
DEV u16 f2bf(float f){ u32 u; __builtin_memcpy(&u,&f,4); u32 r = u + 0x7FFFu + ((u>>16)&1u); return (u16)(r>>16); }

DEV void gl_lds16(const u16* g, u16* l){
  __builtin_amdgcn_global_load_lds((const __attribute__((address_space(1))) void*)g,
                                   (__attribute__((address_space(3))) void*)l, 16, 0, 0);
}

#define BARRIER()  asm volatile("s_barrier" ::: "memory")
#define WAIT_LGKM0() asm volatile("s_waitcnt lgkmcnt(0)" ::: "memory")
#define WAIT_VM(n)  asm volatile("s_waitcnt vmcnt(" #n ")" ::: "memory")

// ---------------- cast fp32 -> bf16 (vectorized) ----------------
__global__ __launch_bounds__(256) void cast_bf16_kernel(const float* __restrict__ in,
                                                        u16* __restrict__ out, int n4){
  int i = blockIdx.x*256 + threadIdx.x;
  int stride = gridDim.x*256;
  for(; i < n4; i += stride){
    float4v v = *(const float4v*)(in + (size_t)i*4);
    u16x4 o;
    for(int e=0;e<4;++e) o[e] = f2bf(v[e]);
    *(u16x4*)(out + (size_t)i*4) = o;
  }
}

// ---------------- transpose + cast: out[c][r] = bf16(in[r][c]) ----------------
__global__ void transpose_cast_kernel(const float* __restrict__ in, u16* __restrict__ out,
                                      int R, int C){
  __shared__ float tile[32][33];
  int c0 = blockIdx.x<<5, r0 = blockIdx.y<<5;
  int tx = threadIdx.x, ty = threadIdx.y;
  for(int k=0;k<32;k+=8) tile[ty+k][tx] = in[(size_t)(r0+ty+k)*C + c0+tx];
  __syncthreads();
  for(int k=0;k<32;k+=8) out[(size_t)(c0+ty+k)*R + r0+tx] = f2bf(tile[tx][ty+k]);
}

// ---------------- 256x256 8-phase GEMM: C[M][N] = A[M][1024] * Bt[N][1024]^T ----------------
// 512 threads = 8 waves (2M x 4N). BK=64, double-buffered LDS (128 KiB), swizzled.
// m201-depth stagger: 1 STAGE/phase, issued 6-7 phases before the vmcnt that drains it.
// EPI==0: Q(*0.125)/K/V scatter bf16.  EPI==1: fp32 Out.
template<int EPI>
__global__ __launch_bounds__(512, 2) void gemm256_kernel(
    const u16* __restrict__ A, const u16* __restrict__ Bt,
    u16* __restrict__ Qb, u16* __restrict__ Kb, u16* __restrict__ Vb,
    float* __restrict__ Out, int Mtot, int tilesx)
{
  __shared__ __align__(16) char smem[131072];
  const int tid = threadIdx.x, lane = tid & 63, wid = tid >> 6;
  const int wr = wid >> 2, wc = wid & 3;

  // XCD-aware bijective swizzle (grid % 8 == 0)
  const int nwg = gridDim.x, chunk = nwg >> 3, orig = blockIdx.x;
  const int wg = (orig & 7)*chunk + (orig >> 3);
  const int by = wg / tilesx, bx = wg - by*tilesx;
  const int m0 = by << 8, n0 = bx << 8;

  f32x4 acc[8][4];
  #pragma unroll
  for(int i=0;i<8;++i)
    #pragma unroll
    for(int j=0;j<4;++j) acc[i][j] = (f32x4){0.f,0.f,0.f,0.f};

  // stage half-tile hi (0,1 = A rows 0-127/128-255; 2,3 = B cols 0-127/128-255) of K-tile t
  auto STAGE = [&](int t, int hi){
    const int bsel = t & 1;
    char* base = smem + bsel*65536 + ((hi>>1)<<15) + ((hi&1)<<14);
    const u16* mat = (hi < 2) ? A : Bt;
    const int rbase = ((hi < 2) ? m0 : n0) + ((hi&1)<<7);
    #pragma unroll
    for(int j=0;j<2;++j){
      int idx = j*512 + tid;
      int r = idx >> 3;
      int c2s = ((idx&7)<<4) ^ ((r&7)<<4);     // pre-swizzled source byte col (involution)
      int grow = rbase + r;
      if(hi < 2 && grow >= Mtot) grow = Mtot - 1;
      const u16* src = mat + (size_t)grow*1024 + t*64 + (c2s>>1);
      u16* dst = (u16*)(base + j*8192 + wid*1024);   // wave-uniform; HW adds lane*16
      gl_lds16(src, dst);
    }
  };

  const int rA   = (lane&15)*128;
  const int csw0 = (((lane>>4)<<4)      ) ^ ((lane&7)<<4);
  const int csw1 = (((lane>>4)<<4) + 64 ) ^ ((lane&7)<<4);

  auto RDA = [&](int bsel, int i, int kk)->short8 {
    const char* p = smem + bsel*65536 + (wr<<14) + (i<<4)*128 + rA + (kk ? csw1 : csw0);
    return *(const short8*)p;
  };
  auto RDB = [&](int bsel, int jn, int kk)->short8 {
    const char* p = smem + bsel*65536 + 32768 + ((wc>>1)<<14)
                  + (((wc&1)<<6) + (jn<<4))*128 + rA + (kk ? csw1 : csw0);
    return *(const short8*)p;
  };

  short8 aR[4][2], b0[2][2], b1[2][2];

  auto MFMA_Q = [&](int qi, int qj, short8 (&bv)[2][2]){
    #pragma unroll
    for(int i=0;i<4;++i)
      #pragma unroll
      for(int j=0;j<2;++j){
        acc[qi*4+i][qj*2+j] = __builtin_amdgcn_mfma_f32_16x16x32_bf16(aR[i][0], bv[j][0], acc[qi*4+i][qj*2+j], 0,0,0);
        acc[qi*4+i][qj*2+j] = __builtin_amdgcn_mfma_f32_16x16x32_bf16(aR[i][1], bv[j][1], acc[qi*4+i][qj*2+j], 0,0,0);
      }
  };

  // 4 phases computing K-tile in buf bs; stage targets (st1..st4, sh1..sh4); lastv -> drain
  auto DO_TILE = [&](int bs, int st1,int sh1, int st2,int sh2, int st3,int sh3, int st4,int sh4, bool lastv){
    // P1: A rows 0-63 + b0; MFMA q(r0,c0)
    #pragma unroll
    for(int i=0;i<4;++i){ aR[i][0]=RDA(bs,i,0); aR[i][1]=RDA(bs,i,1); }
    #pragma unroll
    for(int j=0;j<2;++j){ b0[j][0]=RDB(bs,j,0); b0[j][1]=RDB(bs,j,1); }
    if(st1 < NKT) STAGE(st1, sh1);
    asm volatile("s_waitcnt lgkmcnt(8)" ::: "memory");
    BARRIER(); WAIT_LGKM0();
    __builtin_amdgcn_s_setprio(1); MFMA_Q(0,0,b0); __builtin_amdgcn_s_setprio(0);
    BARRIER();
    // P2: b1; MFMA q(r0,c1)
    #pragma unroll
    for(int j=0;j<2;++j){ b1[j][0]=RDB(bs,2+j,0); b1[j][1]=RDB(bs,2+j,1); }
    if(st2 < NKT) STAGE(st2, sh2);
    BARRIER(); WAIT_LGKM0();
    __builtin_amdgcn_s_setprio(1); MFMA_Q(0,1,b1); __builtin_amdgcn_s_setprio(0);
    BARRIER();
    // P3: A rows 64-127; MFMA q(r1,c1)
    #pragma unroll
    for(int i=0;i<4;++i){ aR[i][0]=RDA(bs,4+i,0); aR[i][1]=RDA(bs,4+i,1); }
    if(st3 < NKT) STAGE(st3, sh3);
    BARRIER(); WAIT_LGKM0();
    __builtin_amdgcn_s_setprio(1); MFMA_Q(1,1,b1); __builtin_amdgcn_s_setprio(0);
    BARRIER();
    // P4: no ds_reads; MFMA q(r1,c0); counted vmcnt then barrier
    if(st4 < NKT) STAGE(st4, sh4);
    BARRIER();
    __builtin_amdgcn_s_setprio(1); MFMA_Q(1,0,b0); __builtin_amdgcn_s_setprio(0);
    if(lastv){ WAIT_VM(0); } else { WAIT_VM(4); }
    BARRIER();
  };

  // prologue: tile0 all 4 halves + tile1 H2,H0; drain tile0 (leave 2 half-tiles in flight)
  STAGE(0,2); STAGE(0,0); STAGE(0,3); STAGE(0,1); STAGE(1,2); STAGE(1,0);
  WAIT_VM(4);
  BARRIER();

  for(int u=0; u<NKT/2; ++u){
    const int tA = 2*u, tB = 2*u+1;
    const bool last = (u == NKT/2-1);
    DO_TILE(0, tB,3,   tB,1,   tA+2,2, tA+2,0, last);   // phases 1-4 (tile tA, buf0)
    DO_TILE(1, tA+2,3, tA+2,1, tB+2,2, tB+2,0, last);   // phases 5-8 (tile tB, buf1)
  }

  __syncthreads();

  if constexpr(EPI==0){
    const int which = n0 >> 10;                 // 256-tile always inside one of Q/K/V
    const int hbase = (n0 & 1023) >> 6;         // 4 heads per tile
    const float sc = (which==0) ? 0.125f : 1.0f;
    u16* dst = (which==0)?Qb:((which==1)?Kb:Vb);
    u16* lC = (u16*)smem;                       // [128][264] bf16 per row-half phase
    for(int rh=0; rh<2; ++rh){
      if(wr == rh){
        #pragma unroll
        for(int i=0;i<8;++i){
          int rr = (i<<4) + ((lane>>4)<<2);
          #pragma unroll
          for(int j=0;j<4;++j){
            int ct = (wc<<6) + (j<<4) + (lane&15);
            #pragma unroll
            for(int r=0;r<4;++r) lC[(rr+r)*264 + ct] = f2bf(acc[i][j][r]*sc);
          }
        }
      }
      __syncthreads();
      for(int it=0; it<8; ++it){
        int idx = it*512 + tid;                 // 0..4095
        int row = idx >> 5, rest = idx & 31, hh = rest>>3, slot = rest&7;
        int mm = m0 + rh*128 + row;
        if(mm < Mtot){
          int b = mm / NTOK, tok = mm - b*NTOK;
          u16x8 v = *(const u16x8*)&lC[row*264 + hh*64 + slot*8];
          *(u16x8*)(dst + (((size_t)(b*NHEAD + hbase + hh)*NTOK + tok)<<6) + slot*8) = v;
        }
      }
      __syncthreads();
    }
  } else {
    float* lF = (float*)smem;                   // [128][132] fp32 per (row-half, col-half)
    for(int ph=0; ph<4; ++ph){
      int rh = ph>>1, ch = ph&1;
      if(wr==rh && (wc>>1)==ch){
        #pragma unroll
        for(int i=0;i<8;++i){
          int rr = (i<<4) + ((lane>>4)<<2);
          #pragma unroll
          for(int j=0;j<4;++j){
            int ct = ((wc&1)<<6) + (j<<4) + (lane&15);
            #pragma unroll
            for(int r=0;r<4;++r) lF[(rr+r)*132 + ct] = acc[i][j][r];
          }
        }
      }
      __syncthreads();
      for(int it=0; it<8; ++it){
        int idx = it*512 + tid;
        int row = idx >> 5, slot = idx & 31;
        int mm = m0 + rh*128 + row;
        if(mm < Mtot){
          float4v v = *(const float4v*)&lF[row*132 + slot*4];
          *(float4v*)(Out + (size_t)mm*1024 + n0 + ch*128 + slot*4) = v;
        }
      }
      __syncthreads();
    }
  }
}

// ---------------- cls attention, flash-decode split-K ----------------
__global__ __launch_bounds__(256) void cls_partial_kernel(
    const u16* __restrict__ Qb, const u16* __restrict__ Kb, const u16* __restrict__ Vb,
    float* __restrict__ part)
{
  __shared__ float qs[64];
  __shared__ float pbuf[4][64];
  __shared__ float wm[4], wl[4];
  __shared__ float wacc[4][64];
  const int tid = threadIdx.x, lane = tid & 63, wv = tid >> 6;
  const int c = blockIdx.x, bh = blockIdx.y;
  const u16* Kh = Kb + (size_t)bh*NTOK*DH;
  const u16* Vh = Vb + (size_t)bh*NTOK*DH;
  if(tid < 64) qs[tid] = bf2f(Qb[(size_t)bh*NTOK*DH + tid]);   // q already *0.125
  __syncthreads();

  const int jb = c*256 + wv*64;
  const int j = jb + lane;
  float s = -1e30f;
  if(j < NTOK){
    const u16* kr = Kh + (size_t)j*DH;
    float dot = 0.f;
    for(int t=0;t<8;++t){
      u16x8 kv = *(const u16x8*)(kr + t*8);
      for(int e=0;e<8;++e) dot += bf2f(kv[e]) * qs[t*8+e];
    }
    s = dot;
  }
  float mw = s;
  for(int off=1; off<64; off<<=1) mw = fmaxf(mw, __shfl_xor(mw, off));
  float p = (j < NTOK) ? __expf(s - mw) : 0.f;
  float lw = p;
  for(int off=1; off<64; off<<=1) lw += __shfl_xor(lw, off);
  pbuf[wv][lane] = p;

  float accd = 0.f;                    // lane = d now
  if(jb < NTOK){
    int nv = NTOK - jb; if(nv > 64) nv = 64;
    for(int jj=0; jj<nv; ++jj)
      accd += pbuf[wv][jj] * bf2f(Vh[(size_t)(jb+jj)*DH + lane]);
  }
  wacc[wv][lane] = accd;
  if(lane==0){ wm[wv]=mw; wl[wv]=lw; }
  __syncthreads();
  if(wv==0){
    float M = fmaxf(fmaxf(wm[0],wm[1]), fmaxf(wm[2],wm[3]));
    float L=0.f, Acc=0.f;
    for(int wi=0; wi<4; ++wi){
      float e = __expf(wm[wi]-M);
      L += wl[wi]*e; Acc += wacc[wi][lane]*e;
    }
    float* dstp = part + ((size_t)bh*13 + c)*68;
    if(lane==0){ dstp[0]=M; dstp[1]=L; }
    dstp[2+lane] = Acc;
  }
}

__global__ __launch_bounds__(64) void cls_reduce_kernel(
    const float* __restrict__ part, u16* __restrict__ Abuf)
{
  const int lane = threadIdx.x, bh = blockIdx.x;
  const float* p0 = part + (size_t)bh*13*68;
  float M = -1e30f;
  for(int i=0;i<13;++i) M = fmaxf(M, p0[i*68]);
  float L=0.f, Acc=0.f;
  for(int i=0;i<13;++i){
    float e = __expf(p0[i*68] - M);
    L += p0[i*68+1]*e;
    Acc += p0[i*68+2+lane]*e;
  }
  int b = bh>>4, h = bh&15;
  Abuf[(size_t)b*NTOK*1024 + h*DH + lane] = f2bf(Acc/L);   // token 0, 128B line
}

// ---------------- axial attention: 1024 blocks (one per (b*16+h, frame)) ----------------
__global__ __launch_bounds__(256) void axial_attn_kernel(
    const u16* __restrict__ Qb, const u16* __restrict__ Kb, const u16* __restrict__ Vb,
    u16* __restrict__ Abuf)
{
  __shared__ u16 lV[64*232];      // V^T: lV[d][ktok]
  __shared__ u16 lP[4*16*232];    // per-wave P tile; reused as per-wave O-stage [16][72]
  const int tid = threadIdx.x, lane = tid & 63, wv = tid >> 6;
  const int bf = blockIdx.x, bh = bf >> 4, fi = bf & 15;
  const u16* Kh = Kb + (size_t)bh*NTOK*DH;
  const u16* Vh = Vb + (size_t)bh*NTOK*DH;
  const u16* Qh = Qb + (size_t)bh*NTOK*DH;

  for(int c = tid; c < 224*8; c += 256){
    int tok = c >> 3, slot = c & 7;
    u16 vals[8];
    if(tok <= 196){
      size_t row = (tok==0) ? 0 : (size_t)(fi*196 + tok)*DH;
      u16x8 v = *(const u16x8*)(Vh + row + slot*8);
      for(int e=0;e<8;++e) vals[e] = v[e];
    } else {
      for(int e=0;e<8;++e) vals[e] = 0;
    }
    for(int e=0;e<8;++e) lV[(slot*8+e)*232 + tok] = vals[e];
  }
  for(int c = tid; c < 4*16*16; c += 256){
    int w2 = c >> 8, rem = c & 255, row = rem >> 4, cc = rem & 15;
    lP[w2*(16*232) + row*232 + 208 + cc] = 0;
  }
  __syncthreads();

  u16* myP = lP + wv*(16*232);
  const int b_i = bh >> 4, h = bh & 15;

  for(int qt = wv; qt < 13; qt += 4){
    int qr = qt*16 + (lane&15);
    int qrc = qr < 196 ? qr : 195;
    size_t qrow = (size_t)(1 + fi*196 + qrc)*DH;
    short8 qa0 = *(const short8*)(Qh + qrow + ((lane>>4)<<3));
    short8 qa1 = *(const short8*)(Qh + qrow + 32 + ((lane>>4)<<3));

    f32x4 s[13];
    for(int t=0;t<13;++t){
      int tok = t*16 + (lane&15);
      int tokc = tok < 197 ? tok : 196;
      size_t krow = (tokc==0) ? 0 : (size_t)(fi*196 + tokc)*DH;
      short8 b0v = *(const short8*)(Kh + krow + ((lane>>4)<<3));
      short8 b1v = *(const short8*)(Kh + krow + 32 + ((lane>>4)<<3));
      f32x4 z = {0.f,0.f,0.f,0.f};
      z = __builtin_amdgcn_mfma_f32_16x16x32_bf16(qa0, b0v, z, 0,0,0);
      z = __builtin_amdgcn_mfma_f32_16x16x32_bf16(qa1, b1v, z, 0,0,0);
      s[t] = z;
    }
    int mycol = lane & 15;
    if(192 + mycol >= 197)
      for(int r=0;r<4;++r) s[12][r] = -1e30f;

    f32x4 mx = s[0];
    for(int t=1;t<13;++t) for(int r=0;r<4;++r) mx[r] = fmaxf(mx[r], s[t][r]);
    for(int off=1; off<16; off<<=1)
      for(int r=0;r<4;++r) mx[r] = fmaxf(mx[r], __shfl_xor(mx[r], off));
    f32x4 lsum = {0.f,0.f,0.f,0.f};
    for(int t=0;t<13;++t) for(int r=0;r<4;++r){
      float p = __expf(s[t][r] - mx[r]); s[t][r] = p; lsum[r] += p;
    }
    for(int off=1; off<16; off<<=1)
      for(int r=0;r<4;++r) lsum[r] += __shfl_xor(lsum[r], off);

    for(int t=0;t<13;++t){
      int tok = t*16 + mycol;
      for(int r=0;r<4;++r) myP[(((lane>>4)<<2)+r)*232 + tok] = f2bf(s[t][r]);
    }

    f32x4 o[4] = {{0.f,0.f,0.f,0.f},{0.f,0.f,0.f,0.f},{0.f,0.f,0.f,0.f},{0.f,0.f,0.f,0.f}};
    for(int t2=0;t2<7;++t2){
      short8 a = *(const short8*)&myP[(lane&15)*232 + t2*32 + ((lane>>4)<<3)];
      for(int nd=0;nd<4;++nd){
        short8 b = *(const short8*)&lV[(nd*16 + (lane&15))*232 + t2*32 + ((lane>>4)<<3)];
        o[nd] = __builtin_amdgcn_mfma_f32_16x16x32_bf16(a, b, o[nd], 0,0,0);
      }
    }

    for(int nd=0; nd<4; ++nd){
      int d = nd*16 + (lane&15);
      for(int r=0;r<4;++r){
        int rr = ((lane>>4)<<2) + r;
        myP[rr*72 + d] = f2bf(o[nd][r] / lsum[r]);
      }
    }
    asm volatile("s_waitcnt lgkmcnt(0)" ::: "memory");
    for(int it=0; it<2; ++it){
      int idx = it*64 + lane;          // 0..127
      int row = idx >> 3, slot = idx & 7;
      int ql = qt*16 + row;
      if(ql < 196){
        u16x8 v = *(const u16x8*)&myP[row*72 + slot*8];
        int tok = 1 + fi*196 + ql;
        *(u16x8*)(Abuf + ((size_t)b_i*NTOK + tok)*1024 + h*DH + slot*8) = v;
      }
    }
  }
}

// ---------------- launcher ----------------
extern "C" void kernel_launch(void* const* d_in, const int* in_sizes, int n_in,
                              void* d_out, int out_size, void* d_ws, size_t ws_size,
                              hipStream_t stream) {
  const float* x     = (const float*)d_in[0];
  const float* wqkv  = (const float*)d_in[1];
  const float* wout  = (const float*)d_in[2];
  float* out = (float*)d_out;
  char* ws = (char*)d_ws;

  u16* xb     = (u16*)(ws);                      // 25,698,304  [M][1024] bf16
  u16* Abuf   = xb;                              // attn output (aliases xb)
  u16* wqkvT  = (u16*)(ws + 25698304);           //  6,291,456  [3072][1024] bf16
  float* clsPart = (float*)(ws + 25698304);      // aliases wqkvT (dead after gemm<0>)
  u16* woutT  = (u16*)(ws + 31989760);           //  2,097,152  [1024][1024] bf16
  u16* Qb     = (u16*)(ws + 34086912);           // 25,698,304  [64][3137][64] bf16 (scaled)
  u16* Kb     = (u16*)(ws + 59785216);
  u16* Vb     = (u16*)(ws + 85483520);           // end 111,181,824

  cast_bf16_kernel<<<dim3(2048), dim3(256), 0, stream>>>(x, xb, (MROWS*1024)/4);
  transpose_cast_kernel<<<dim3(96,32), dim3(32,8), 0, stream>>>(wqkv, wqkvT, 1024, 3072);
  transpose_cast_kernel<<<dim3(32,32), dim3(32,8), 0, stream>>>(wout, woutT, 1024, 1024);

  // M-tiles = ceil(12548/256) = 50; gemm<0>: 50x12 = 600 blocks; gemm<1>: 50x4 = 200
  gemm256_kernel<0><<<dim3(600), dim3(512), 0, stream>>>(xb, wqkvT, Qb, Kb, Vb, nullptr, MROWS, 12);

  cls_partial_kernel<<<dim3(13,64), dim3(256), 0, stream>>>(Qb, Kb, Vb, clsPart);
  cls_reduce_kernel<<<dim3(64), dim3(64), 0, stream>>>(clsPart, Abuf);
  axial_attn_kernel<<<dim3(1024), dim3(256), 0, stream>>>(Qb, Kb, Vb, Abuf);

  gemm256_kernel<1><<<dim3(200), dim3(512), 0, stream>>>(Abuf, woutT, nullptr, nullptr, nullptr, out, MROWS, 4);
}

// Round 6
// 206.537 us; speedup vs baseline: 6.0176x; 1.0301x over previous
//
#include <hip/hip_runtime.h>
#include <stdint.h>

typedef unsigned short u16;
typedef unsigned int u32;
typedef __attribute__((ext_vector_type(4))) float f32x4;
typedef __attribute__((ext_vector_type(4))) float float4v;
typedef __attribute__((ext_vector_type(8))) short short8;
typedef __attribute__((ext_vector_type(4))) u32 u32x4;
typedef __attribute__((ext_vector_type(4))) u16 u16x4;
typedef __attribute__((ext_vector_type(8))) u16 u16x8;

#define DEV static __device__ __forceinline__

#define NTOK 3137
#define MROWS 12548
#define NHEAD 16
#define DH 64
#define NKT 16            // K=1024 / BK=64

DEV float bf2f(u16 h){ u32 u = ((u32)h)<<16; float f; __builtin_memcpy(&f,&u,4); return f; }
DEV u16 f2bf(float f){ u32 u; __builtin_memcpy(&u,&f,4); u32 r = u + 0x7FFFu + ((u>>16)&1u); return (u16)(r>>16); }

DEV void gl_lds16(const u16* g, u16* l){
  __builtin_amdgcn_global_load_lds((const __attribute__((address_space(1))) void*)g,
                                   (__attribute__((address_space(3))) void*)l, 16, 0, 0);
}

#define BARRIER()  asm volatile("s_barrier" ::: "memory")
#define WAIT_LGKM0() asm volatile("s_waitcnt lgkmcnt(0)" ::: "memory")
#define WAIT_VM(n)  asm volatile("s_waitcnt vmcnt(" #n ")" ::: "memory")

// ---------------- fused prep: cast x->bf16; transpose+cast both weights ----------------
__global__ __launch_bounds__(256) void prep_kernel(
    const float* __restrict__ x, const float* __restrict__ wqkv, const float* __restrict__ wout,
    u16* __restrict__ xb, u16* __restrict__ wqkvT, u16* __restrict__ woutT)
{
  __shared__ float tile[32][33];
  const int bid = blockIdx.x, tid = threadIdx.x;
  if(bid < 2048){
    const int n4 = (MROWS*1024)/4;
    for(int i = bid*256 + tid; i < n4; i += 2048*256){
      float4v v = *(const float4v*)(x + (size_t)i*4);
      u16x4 o;
      for(int e=0;e<4;++e) o[e] = f2bf(v[e]);
      *(u16x4*)(xb + (size_t)i*4) = o;
    }
  } else {
    const float* in; u16* out; int C, c0, r0;
    if(bid < 2048+3072){
      int tb = bid - 2048; in = wqkv; out = wqkvT; C = 3072;
      c0 = (tb%96)<<5; r0 = (tb/96)<<5;
    } else {
      int tb = bid - 5120; in = wout; out = woutT; C = 1024;
      c0 = (tb&31)<<5; r0 = (tb>>5)<<5;
    }
    const int R = 1024;
    int tx = tid&31, ty = tid>>5;
    for(int k=0;k<32;k+=8) tile[ty+k][tx] = in[(size_t)(r0+ty+k)*C + c0+tx];
    __syncthreads();
    for(int k=0;k<32;k+=8) out[(size_t)(c0+ty+k)*R + r0+tx] = f2bf(tile[tx][ty+k]);
  }
}

// ---------------- 256x256 GEMM, K-half phased pipeline ----------------
// 512 thr = 8 waves (2M x 4N). BK=64 split into 2 K-halves of 32.
// LDS: [buf][khalf] regions of 32KB (A 16KB rows-as-pairs + B 16KB), 128KB total.
// Per phase: 12 ds_read_b128 + 1 stage-unit (4 gl_lds16) + 32 MFMA; uniform vmcnt(8).
// EPI==0: Q(*0.125)/K/V scatter bf16.  EPI==1: fp32 Out.
template<int EPI>
__global__ __launch_bounds__(512, 2) void gemm256_kernel(
    const u16* __restrict__ A, const u16* __restrict__ Bt,
    u16* __restrict__ Qb, u16* __restrict__ Kb, u16* __restrict__ Vb,
    float* __restrict__ Out, int Mtot, int tilesx)
{
  __shared__ __align__(16) char smem[131072];
  const int tid = threadIdx.x, lane = tid & 63, wid = tid >> 6;
  const int wr = wid >> 2, wc = wid & 3;

  // XCD-aware bijective swizzle (grid % 8 == 0)
  const int nwg = gridDim.x, chunk = nwg >> 3, orig = blockIdx.x;
  const int wg = (orig & 7)*chunk + (orig >> 3);
  const int by = wg / tilesx, bx = wg - by*tilesx;
  const int m0 = by << 8, n0 = bx << 8;

  f32x4 acc[8][4];
  #pragma unroll
  for(int i=0;i<8;++i)
    #pragma unroll
    for(int j=0;j<4;++j) acc[i][j] = (f32x4){0.f,0.f,0.f,0.f};

  // Region layout: pair p (2 consecutive rows), 8 slots of 16B per pair (128B),
  // slot' = (subrow*4 + kslot16B) ^ (p&7).  Linear dest for gl_lds; swizzled source.
  auto STAGE = [&](int t, int kh){
    const int bsel = t & 1;
    char* rbase = smem + bsel*65536 + kh*32768;
    #pragma unroll
    for(int c=0;c<4;++c){
      const int half = c & 1;              // 8KB half of the 16KB part
      const int isB  = c >> 1;
      int slotpos = (half<<9) + tid;       // 0..1023 16B-slots within part
      int pair = slotpos >> 3;
      int sl   = (slotpos & 7) ^ (pair & 7);
      int grow = (isB ? n0 : m0) + pair*2 + (sl>>2);
      if(!isB && grow >= Mtot) grow = Mtot - 1;
      const u16* src = (isB ? Bt : A) + (size_t)grow*1024 + t*64 + kh*32 + (sl&3)*8;
      u16* dst = (u16*)(rbase + (isB<<14) + (half<<13) + wid*1024);  // +lane*16 by HW
      gl_lds16(src, dst);
    }
  };

  // fragment-read lane constants (pair&7 == (lane&15)>>1 for all frags)
  const int pl = (lane&15)>>1;
  const int sprime = ((((lane&1)<<2) | (lane>>4)) ^ pl);
  const int laneoff = pl*128 + sprime*16;

  auto PHASE = [&](int bsel, int t, int kh, int stT, int stKh, int vmode){
    short8 af[8], bfv[4];
    const char* rb = smem + bsel*65536 + kh*32768;
    #pragma unroll
    for(int i=0;i<8;++i) af[i]  = *(const short8*)(rb + (wr<<13) + (i<<10) + laneoff);
    #pragma unroll
    for(int j=0;j<4;++j) bfv[j] = *(const short8*)(rb + 16384 + (wc<<12) + (j<<10) + laneoff);
    if(stT < NKT) STAGE(stT, stKh);
    asm volatile("s_waitcnt lgkmcnt(8)" ::: "memory");
    BARRIER();
    WAIT_LGKM0();
    __builtin_amdgcn_s_setprio(1);
    #pragma unroll
    for(int i=0;i<8;++i)
      #pragma unroll
      for(int j=0;j<4;++j)
        acc[i][j] = __builtin_amdgcn_mfma_f32_16x16x32_bf16(af[i], bfv[j], acc[i][j], 0,0,0);
    __builtin_amdgcn_s_setprio(0);
    if(vmode==0){ WAIT_VM(8); } else if(vmode==1){ WAIT_VM(4); } else { WAIT_VM(0); }
    BARRIER();
  };

  // prologue: units (0,k0),(0,k1),(1,k0) = 12 per-wave loads; drain (0,k0)
  STAGE(0,0); STAGE(0,1); STAGE(1,0);
  WAIT_VM(8);
  BARRIER();

  for(int u=0; u<7; ++u){
    const int tA = 2*u, tB = 2*u+1;
    PHASE(0, tA, 0, tA+1, 1, 0);
    PHASE(0, tA, 1, tA+2, 0, 0);
    PHASE(1, tB, 0, tB+1, 1, 0);
    PHASE(1, tB, 1, tB+2, 0, 0);
  }
  PHASE(0, 14, 0, 15, 1, 0);
  PHASE(0, 14, 1, 16, 0, 1);   // stage skipped; drain (15,k0)
  PHASE(1, 15, 0, 16, 1, 2);   // drain (15,k1)
  PHASE(1, 15, 1, 16, 0, 2);

  __syncthreads();

  if constexpr(EPI==0){
    const int which = n0 >> 10;                 // 256-tile inside one of Q/K/V
    const int hbase = (n0 & 1023) >> 6;         // 4 heads per tile
    const float sc = (which==0) ? 0.125f : 1.0f;
    u16* dst = (which==0)?Qb:((which==1)?Kb:Vb);
    u16* lC = (u16*)smem;                       // [128][264] bf16 per row-half
    for(int rh=0; rh<2; ++rh){
      if(wr == rh){
        #pragma unroll
        for(int i=0;i<8;++i){
          int rr = (i<<4) + ((lane>>4)<<2);
          #pragma unroll
          for(int j=0;j<4;++j){
            int ct = (wc<<6) + (j<<4) + (lane&15);
            #pragma unroll
            for(int r=0;r<4;++r) lC[(rr+r)*264 + ct] = f2bf(acc[i][j][r]*sc);
          }
        }
      }
      __syncthreads();
      for(int it=0; it<8; ++it){
        int idx = it*512 + tid;                 // 0..4095
        int row = idx >> 5, rest = idx & 31, hh = rest>>3, slot = rest&7;
        int mm = m0 + rh*128 + row;
        if(mm < Mtot){
          int b = mm / NTOK, tok = mm - b*NTOK;
          u16x8 v = *(const u16x8*)&lC[row*264 + hh*64 + slot*8];
          *(u16x8*)(dst + (((size_t)(b*NHEAD + hbase + hh)*NTOK + tok)<<6) + slot*8) = v;
        }
      }
      __syncthreads();
    }
  } else {
    float* lF = (float*)smem;                   // [128][132] fp32 per (rh,ch)
    for(int ph=0; ph<4; ++ph){
      int rh = ph>>1, ch = ph&1;
      if(wr==rh && (wc>>1)==ch){
        #pragma unroll
        for(int i=0;i<8;++i){
          int rr = (i<<4) + ((lane>>4)<<2);
          #pragma unroll
          for(int j=0;j<4;++j){
            int ct = ((wc&1)<<6) + (j<<4) + (lane&15);
            #pragma unroll
            for(int r=0;r<4;++r) lF[(rr+r)*132 + ct] = acc[i][j][r];
          }
        }
      }
      __syncthreads();
      for(int it=0; it<8; ++it){
        int idx = it*512 + tid;
        int row = idx >> 5, slot = idx & 31;
        int mm = m0 + rh*128 + row;
        if(mm < Mtot){
          float4v v = *(const float4v*)&lF[row*132 + slot*4];
          *(float4v*)(Out + (size_t)mm*1024 + n0 + ch*128 + slot*4) = v;
        }
      }
      __syncthreads();
    }
  }
}

// ---------------- fused attention: blocks 0-1023 axial, 1024-1855 cls partials ----------------
__global__ __launch_bounds__(256) void attn_kernel(
    const u16* __restrict__ Qb, const u16* __restrict__ Kb, const u16* __restrict__ Vb,
    float* __restrict__ part, u16* __restrict__ Abuf)
{
  __shared__ u16 lV[64*232];
  __shared__ u16 lP[4*16*232];
  __shared__ float qs[64];
  __shared__ float pbuf[4][64];
  __shared__ float wmx[4], wls[4];
  __shared__ float wacc[4][64];
  const int tid = threadIdx.x, lane = tid & 63, wv = tid >> 6;

  if(blockIdx.x >= 1024){
    // ---- cls partial: idx -> (chunk c, head bh) ----
    const int idx = blockIdx.x - 1024;
    const int c = idx >> 6, bh = idx & 63;
    const u16* Kh = Kb + (size_t)bh*NTOK*DH;
    const u16* Vh = Vb + (size_t)bh*NTOK*DH;
    if(tid < 64) qs[tid] = bf2f(Qb[(size_t)bh*NTOK*DH + tid]);   // q already *0.125
    __syncthreads();

    const int jb = c*256 + wv*64;
    const int j = jb + lane;
    float s = -1e30f;
    if(j < NTOK){
      const u16* kr = Kh + (size_t)j*DH;
      float dot = 0.f;
      for(int t=0;t<8;++t){
        u16x8 kv = *(const u16x8*)(kr + t*8);
        for(int e=0;e<8;++e) dot += bf2f(kv[e]) * qs[t*8+e];
      }
      s = dot;
    }
    float mw = s;
    for(int off=1; off<64; off<<=1) mw = fmaxf(mw, __shfl_xor(mw, off));
    float p = (j < NTOK) ? __expf(s - mw) : 0.f;
    float lw = p;
    for(int off=1; off<64; off<<=1) lw += __shfl_xor(lw, off);
    pbuf[wv][lane] = p;

    float accd = 0.f;                    // lane = d now
    if(jb < NTOK){
      int nv = NTOK - jb; if(nv > 64) nv = 64;
      for(int jj=0; jj<nv; ++jj)
        accd += pbuf[wv][jj] * bf2f(Vh[(size_t)(jb+jj)*DH + lane]);
    }
    wacc[wv][lane] = accd;
    if(lane==0){ wmx[wv]=mw; wls[wv]=lw; }
    __syncthreads();
    if(wv==0){
      float M = fmaxf(fmaxf(wmx[0],wmx[1]), fmaxf(wmx[2],wmx[3]));
      float L=0.f, Acc=0.f;
      for(int wi=0; wi<4; ++wi){
        float e = __expf(wmx[wi]-M);
        L += wls[wi]*e; Acc += wacc[wi][lane]*e;
      }
      float* dstp = part + ((size_t)bh*13 + c)*68;
      if(lane==0){ dstp[0]=M; dstp[1]=L; }
      dstp[2+lane] = Acc;
    }
    return;
  }

  // ---- axial attention ----
  const int bf = blockIdx.x, bh = bf >> 4, fi = bf & 15;
  const u16* Kh = Kb + (size_t)bh*NTOK*DH;
  const u16* Vh = Vb + (size_t)bh*NTOK*DH;
  const u16* Qh = Qb + (size_t)bh*NTOK*DH;

  for(int c = tid; c < 224*8; c += 256){
    int tok = c >> 3, slot = c & 7;
    u16 vals[8];
    if(tok <= 196){
      size_t row = (tok==0) ? 0 : (size_t)(fi*196 + tok)*DH;
      u16x8 v = *(const u16x8*)(Vh + row + slot*8);
      for(int e=0;e<8;++e) vals[e] = v[e];
    } else {
      for(int e=0;e<8;++e) vals[e] = 0;
    }
    for(int e=0;e<8;++e) lV[(slot*8+e)*232 + tok] = vals[e];
  }
  for(int c = tid; c < 4*16*16; c += 256){
    int w2 = c >> 8, rem = c & 255, row = rem >> 4, cc = rem & 15;
    lP[w2*(16*232) + row*232 + 208 + cc] = 0;
  }
  __syncthreads();

  u16* myP = lP + wv*(16*232);
  const int b_i = bh >> 4, h = bh & 15;

  for(int qt = wv; qt < 13; qt += 4){
    int qr = qt*16 + (lane&15);
    int qrc = qr < 196 ? qr : 195;
    size_t qrow = (size_t)(1 + fi*196 + qrc)*DH;
    short8 qa0 = *(const short8*)(Qh + qrow + ((lane>>4)<<3));
    short8 qa1 = *(const short8*)(Qh + qrow + 32 + ((lane>>4)<<3));

    f32x4 s[13];
    for(int t=0;t<13;++t){
      int tok = t*16 + (lane&15);
      int tokc = tok < 197 ? tok : 196;
      size_t krow = (tokc==0) ? 0 : (size_t)(fi*196 + tokc)*DH;
      short8 b0v = *(const short8*)(Kh + krow + ((lane>>4)<<3));
      short8 b1v = *(const short8*)(Kh + krow + 32 + ((lane>>4)<<3));
      f32x4 z = {0.f,0.f,0.f,0.f};
      z = __builtin_amdgcn_mfma_f32_16x16x32_bf16(qa0, b0v, z, 0,0,0);
      z = __builtin_amdgcn_mfma_f32_16x16x32_bf16(qa1, b1v, z, 0,0,0);
      s[t] = z;
    }
    int mycol = lane & 15;
    if(192 + mycol >= 197)
      for(int r=0;r<4;++r) s[12][r] = -1e30f;

    f32x4 mx = s[0];
    for(int t=1;t<13;++t) for(int r=0;r<4;++r) mx[r] = fmaxf(mx[r], s[t][r]);
    for(int off=1; off<16; off<<=1)
      for(int r=0;r<4;++r) mx[r] = fmaxf(mx[r], __shfl_xor(mx[r], off));
    f32x4 lsum = {0.f,0.f,0.f,0.f};
    for(int t=0;t<13;++t) for(int r=0;r<4;++r){
      float p = __expf(s[t][r] - mx[r]); s[t][r] = p; lsum[r] += p;
    }
    for(int off=1; off<16; off<<=1)
      for(int r=0;r<4;++r) lsum[r] += __shfl_xor(lsum[r], off);

    for(int t=0;t<13;++t){
      int tok = t*16 + mycol;
      for(int r=0;r<4;++r) myP[(((lane>>4)<<2)+r)*232 + tok] = f2bf(s[t][r]);
    }

    f32x4 o[4] = {{0.f,0.f,0.f,0.f},{0.f,0.f,0.f,0.f},{0.f,0.f,0.f,0.f},{0.f,0.f,0.f,0.f}};
    for(int t2=0;t2<7;++t2){
      short8 a = *(const short8*)&myP[(lane&15)*232 + t2*32 + ((lane>>4)<<3)];
      for(int nd=0;nd<4;++nd){
        short8 b = *(const short8*)&lV[(nd*16 + (lane&15))*232 + t2*32 + ((lane>>4)<<3)];
        o[nd] = __builtin_amdgcn_mfma_f32_16x16x32_bf16(a, b, o[nd], 0,0,0);
      }
    }

    for(int nd=0; nd<4; ++nd){
      int d = nd*16 + (lane&15);
      for(int r=0;r<4;++r){
        int rr = ((lane>>4)<<2) + r;
        myP[rr*72 + d] = f2bf(o[nd][r] / lsum[r]);
      }
    }
    asm volatile("s_waitcnt lgkmcnt(0)" ::: "memory");
    for(int it=0; it<2; ++it){
      int idx = it*64 + lane;          // 0..127
      int row = idx >> 3, slot = idx & 7;
      int ql = qt*16 + row;
      if(ql < 196){
        u16x8 v = *(const u16x8*)&myP[row*72 + slot*8];
        int tok = 1 + fi*196 + ql;
        *(u16x8*)(Abuf + ((size_t)b_i*NTOK + tok)*1024 + h*DH + slot*8) = v;
      }
    }
  }
}

__global__ __launch_bounds__(64) void cls_reduce_kernel(
    const float* __restrict__ part, u16* __restrict__ Abuf)
{
  const int lane = threadIdx.x, bh = blockIdx.x;
  const float* p0 = part + (size_t)bh*13*68;
  float M = -1e30f;
  for(int i=0;i<13;++i) M = fmaxf(M, p0[i*68]);
  float L=0.f, Acc=0.f;
  for(int i=0;i<13;++i){
    float e = __expf(p0[i*68] - M);
    L += p0[i*68+1]*e;
    Acc += p0[i*68+2+lane]*e;
  }
  int b = bh>>4, h = bh&15;
  Abuf[(size_t)b*NTOK*1024 + h*DH + lane] = f2bf(Acc/L);   // token 0, 128B line
}

// ---------------- launcher ----------------
extern "C" void kernel_launch(void* const* d_in, const int* in_sizes, int n_in,
                              void* d_out, int out_size, void* d_ws, size_t ws_size,
                              hipStream_t stream) {
  const float* x     = (const float*)d_in[0];
  const float* wqkv  = (const float*)d_in[1];
  const float* wout  = (const float*)d_in[2];
  float* out = (float*)d_out;
  char* ws = (char*)d_ws;

  u16* xb     = (u16*)(ws);                      // 25,698,304  [M][1024] bf16
  u16* Abuf   = xb;                              // attn output (aliases xb)
  u16* wqkvT  = (u16*)(ws + 25698304);           //  6,291,456  [3072][1024] bf16
  float* clsPart = (float*)(ws + 25698304);      // aliases wqkvT (dead after gemm<0>)
  u16* woutT  = (u16*)(ws + 31989760);           //  2,097,152  [1024][1024] bf16
  u16* Qb     = (u16*)(ws + 34086912);           // 25,698,304  [64][3137][64] bf16 (scaled)
  u16* Kb     = (u16*)(ws + 59785216);
  u16* Vb     = (u16*)(ws + 85483520);           // end 111,181,824

  prep_kernel<<<dim3(6144), dim3(256), 0, stream>>>(x, wqkv, wout, xb, wqkvT, woutT);

  gemm256_kernel<0><<<dim3(600), dim3(512), 0, stream>>>(xb, wqkvT, Qb, Kb, Vb, nullptr, MROWS, 12);

  attn_kernel<<<dim3(1856), dim3(256), 0, stream>>>(Qb, Kb, Vb, clsPart, Abuf);
  cls_reduce_kernel<<<dim3(64), dim3(64), 0, stream>>>(clsPart, Abuf);

  gemm256_kernel<1><<<dim3(200), dim3(512), 0, stream>>>(Abuf, woutT, nullptr, nullptr, nullptr, out, MROWS, 4);
}